// Round 8
// baseline (489.659 us; speedup 1.0000x reference)
//
#include <hip/hip_runtime.h>
#include <math.h>

// Problem constants (from reference): B=32, N_SOURCES=262144, H=W=256
#define BATCH 32
#define NSRC  262144
#define HH    256
#define WW    256
#define HW    (HH * WW)
#define NBLK  16          // partial-reduce blocks per batch
#define SRC_PER_THREAD 8  // scatter: sources per thread

// ws layout: float4 partials[BATCH][NBLK] = {xmin, xmax, ymin, ymax}  (8 KB)

__global__ void reduce_zero_kernel(const float* __restrict__ spatial,
                                   float4* __restrict__ partials,
                                   float* __restrict__ out) {
    const int b   = blockIdx.y;   // batch
    const int blk = blockIdx.x;   // chunk within batch
    const int tid = threadIdx.x;  // 0..255

    const int chunk = HW / NBLK;  // 4096 elements
    const float* xs = spatial + (size_t)b * 2 * HW + (size_t)blk * chunk;
    const float* ys = xs + HW;

    float xmn = 1e30f, xmx = -1e30f, ymn = 1e30f, ymx = -1e30f;
    const float4* xs4 = (const float4*)xs;
    const float4* ys4 = (const float4*)ys;
    // 4096 / 256 threads = 16 floats = 4 float4 per thread
#pragma unroll
    for (int k = 0; k < 4; k++) {
        float4 vx = xs4[k * 256 + tid];
        float4 vy = ys4[k * 256 + tid];
        xmn = fminf(xmn, fminf(fminf(vx.x, vx.y), fminf(vx.z, vx.w)));
        xmx = fmaxf(xmx, fmaxf(fmaxf(vx.x, vx.y), fmaxf(vx.z, vx.w)));
        ymn = fminf(ymn, fminf(fminf(vy.x, vy.y), fminf(vy.z, vy.w)));
        ymx = fmaxf(ymx, fmaxf(fmaxf(vy.x, vy.y), fmaxf(vy.z, vy.w)));
    }
    // wave (64-lane) reduce
#pragma unroll
    for (int off = 32; off > 0; off >>= 1) {
        xmn = fminf(xmn, __shfl_down(xmn, off));
        xmx = fmaxf(xmx, __shfl_down(xmx, off));
        ymn = fminf(ymn, __shfl_down(ymn, off));
        ymx = fmaxf(ymx, __shfl_down(ymx, off));
    }
    __shared__ float4 s[4];
    if ((tid & 63) == 0) s[tid >> 6] = make_float4(xmn, xmx, ymn, ymx);
    __syncthreads();
    if (tid == 0) {
        float4 r = s[0];
#pragma unroll
        for (int wv = 1; wv < 4; wv++) {
            float4 t = s[wv];
            r.x = fminf(r.x, t.x); r.y = fmaxf(r.y, t.y);
            r.z = fminf(r.z, t.z); r.w = fmaxf(r.w, t.w);
        }
        partials[b * NBLK + blk] = r;
    }

    // Zero the output (harness poisons it with 0xAA before every launch).
    // Grid threads = BATCH*NBLK*256 = 131072; out float4s = BATCH*HW/4 = 524288 -> 4 each.
    float4* out4 = (float4*)out;
    const int gid = (b * NBLK + blk) * 256 + tid;
#pragma unroll
    for (int k = 0; k < 4; k++) {
        out4[k * 131072 + gid] = make_float4(0.f, 0.f, 0.f, 0.f);
    }
}

__global__ void scatter_kernel(const float* __restrict__ point_rates,
                               const float* __restrict__ gia,
                               const float2* __restrict__ coords,
                               const float4* __restrict__ partials,
                               float* __restrict__ out) {
    const int b   = blockIdx.y;
    const int tid = threadIdx.x;

    // Fold the NBLK=16 partials for this batch (redundantly per block; cheap).
    __shared__ float4 sbox;
    if (tid < 64) {  // whole first wave active so shuffles are defined
        float4 p = make_float4(1e30f, -1e30f, 1e30f, -1e30f);
        if (tid < NBLK) p = partials[b * NBLK + tid];
        float xmn = p.x, xmx = p.y, ymn = p.z, ymx = p.w;
#pragma unroll
        for (int off = 8; off > 0; off >>= 1) {
            xmn = fminf(xmn, __shfl_down(xmn, off));
            xmx = fmaxf(xmx, __shfl_down(xmx, off));
            ymn = fminf(ymn, __shfl_down(ymn, off));
            ymx = fmaxf(ymx, __shfl_down(ymx, off));
        }
        if (tid == 0) sbox = make_float4(xmn, xmx, ymn, ymx);
    }
    __syncthreads();
    const float xmin = sbox.x, xmax = sbox.y, ymin = sbox.z, ymax = sbox.w;
    const float dx = __fsub_rn(xmax, xmin);
    const float dy = __fsub_rn(ymax, ymin);
    // RECIPROCAL-MULTIPLY normalization probe (the idiomatic hand-optimized
    // numpy transcription):
    //   inv = 1.0/(xmax-xmin)            -- ONE correctly-rounded f32 rcp
    //   nx  = (sx - xmin) * inv          -- f32 mul (NOT a division)
    //   u   = nx * 255                   -- f32 mul
    // Distinct from tried R1 (true div) and R6 (fused 255/dx). All pinned
    // correctly-rounded f32; rintf = half-even = np.round.
    const float invx = __fdiv_rn(1.0f, dx);
    const float invy = __fdiv_rn(1.0f, dy);

    const float* pr = point_rates + (size_t)b * NSRC;
    const float* g  = gia + (size_t)b * HW;
    float*       o  = out + (size_t)b * HW;

    const int base = blockIdx.x * (256 * SRC_PER_THREAD);
#pragma unroll
    for (int k = 0; k < SRC_PER_THREAD; k++) {
        const int i = base + k * 256 + tid;   // coalesced
        const float2 c = coords[i];
        const float  r = pr[i];
        // Out-of-view sources have em == 0 exactly in the reference -> skip.
        if (c.x < xmin || c.x > xmax || c.y < ymin || c.y > ymax) continue;
        const float nx = __fmul_rn(__fsub_rn(c.x, xmin), invx);
        const float ny = __fmul_rn(__fsub_rn(c.y, ymin), invy);
        int px = (int)rintf(__fmul_rn(nx, 255.0f));
        int py = (int)rintf(__fmul_rn(ny, 255.0f));
        // rcp-mul form can overshoot [0,255] by an ulp at the edges: clip
        // (reference applies np.clip unconditionally).
        px = px < 0 ? 0 : (px > 255 ? 255 : px);
        py = py < 0 ? 0 : (py > 255 ? 255 : py);
        const int idx = py * WW + px;
        const float em = r * g[idx];
        atomicAdd(&o[idx], em);
    }
}

extern "C" void kernel_launch(void* const* d_in, const int* in_sizes, int n_in,
                              void* d_out, int out_size, void* d_ws, size_t ws_size,
                              hipStream_t stream) {
    const float* point_rates = (const float*)d_in[0];  // (B, NSRC)
    const float* spatial     = (const float*)d_in[1];  // (B, 2, H, W)
    const float* gia         = (const float*)d_in[2];  // (B, H, W)
    const float* coords      = (const float*)d_in[3];  // (NSRC, 2)
    float* out = (float*)d_out;                        // (B, 1, H, W)
    float4* partials = (float4*)d_ws;                  // 8 KB

    reduce_zero_kernel<<<dim3(NBLK, BATCH), 256, 0, stream>>>(spatial, partials, out);

    scatter_kernel<<<dim3(NSRC / (256 * SRC_PER_THREAD), BATCH), 256, 0, stream>>>(
        point_rates, gia, (const float2*)coords, partials, out);
}

// Round 9
// 291.862 us; speedup vs baseline: 1.6777x; 1.6777x over previous
//
#include <hip/hip_runtime.h>
#include <math.h>

// Problem constants: B=32, N_SOURCES=262144, H=W=256
#define BATCH 32
#define NSRC  262144
#define HH    256
#define WW    256
#define HW    (HH * WW)
#define NBLK  16            // partial-reduce blocks per batch
#define NBANDS 8            // row-bands per image
#define BAND_ROWS 32        // 256/NBANDS
#define BAND_PIX  (BAND_ROWS * WW)   // 8192 floats = 32 KB LDS
#define OVF_CAP   262144

// ws layout:
//   [0, 8192)            float4 partials[BATCH][NBLK] = {xmin,xmax,ymin,ymax}
//   [8192, 8196)         u32 ovf_count
//   [8448, 8448+1MB)     u32 ovf_entries[OVF_CAP]  (entry = b<<18 | src_idx)
//   [1057024, +16.8MB)   u16 routes[BATCH][NSRC]
#define WS_OVF_COUNT_OFF 8192
#define WS_OVF_ENT_OFF   8448
#define WS_ROUTES_OFF    1057024
#define WS_FAST_BYTES    (WS_ROUTES_OFF + (size_t)BATCH * NSRC * 2)

// ---------- Kernel A: per-batch bounding-box partials ----------
__global__ void box_kernel(const float* __restrict__ spatial,
                           float4* __restrict__ partials,
                           unsigned int* __restrict__ ovf_count,  // may be null
                           int clear_ovf) {
    const int b   = blockIdx.y;
    const int blk = blockIdx.x;
    const int tid = threadIdx.x;  // 0..255

    if (clear_ovf && blk == 0 && b == 0 && tid == 0) *ovf_count = 0u;

    const int chunk = HW / NBLK;  // 4096
    const float* xs = spatial + (size_t)b * 2 * HW + (size_t)blk * chunk;
    const float* ys = xs + HW;

    float xmn = 1e30f, xmx = -1e30f, ymn = 1e30f, ymx = -1e30f;
    const float4* xs4 = (const float4*)xs;
    const float4* ys4 = (const float4*)ys;
#pragma unroll
    for (int k = 0; k < 4; k++) {
        float4 vx = xs4[k * 256 + tid];
        float4 vy = ys4[k * 256 + tid];
        xmn = fminf(xmn, fminf(fminf(vx.x, vx.y), fminf(vx.z, vx.w)));
        xmx = fmaxf(xmx, fmaxf(fmaxf(vx.x, vx.y), fmaxf(vx.z, vx.w)));
        ymn = fminf(ymn, fminf(fminf(vy.x, vy.y), fminf(vy.z, vy.w)));
        ymx = fmaxf(ymx, fmaxf(fmaxf(vy.x, vy.y), fmaxf(vy.z, vy.w)));
    }
#pragma unroll
    for (int off = 32; off > 0; off >>= 1) {
        xmn = fminf(xmn, __shfl_down(xmn, off));
        xmx = fmaxf(xmx, __shfl_down(xmx, off));
        ymn = fminf(ymn, __shfl_down(ymn, off));
        ymx = fmaxf(ymx, __shfl_down(ymx, off));
    }
    __shared__ float4 s[4];
    if ((tid & 63) == 0) s[tid >> 6] = make_float4(xmn, xmx, ymn, ymx);
    __syncthreads();
    if (tid == 0) {
        float4 r = s[0];
#pragma unroll
        for (int wv = 1; wv < 4; wv++) {
            float4 t = s[wv];
            r.x = fminf(r.x, t.x); r.y = fmaxf(r.y, t.y);
            r.z = fminf(r.z, t.z); r.w = fmaxf(r.w, t.w);
        }
        partials[b * NBLK + blk] = r;
    }
}

// Fold the 16 box partials for batch b (first wave), broadcast via LDS.
__device__ __forceinline__ float4 fold_box(const float4* __restrict__ partials,
                                           int b, int tid, float4* sbox) {
    if (tid < 64) {
        float4 p = make_float4(1e30f, -1e30f, 1e30f, -1e30f);
        if (tid < NBLK) p = partials[b * NBLK + tid];
        float xmn = p.x, xmx = p.y, ymn = p.z, ymx = p.w;
#pragma unroll
        for (int off = 8; off > 0; off >>= 1) {
            xmn = fminf(xmn, __shfl_down(xmn, off));
            xmx = fmaxf(xmx, __shfl_down(xmx, off));
            ymn = fminf(ymn, __shfl_down(ymn, off));
            ymx = fmaxf(ymx, __shfl_down(ymx, off));
        }
        if (tid == 0) *sbox = make_float4(xmn, xmx, ymn, ymx);
    }
    __syncthreads();
    return *sbox;
}

// Verified reference pipeline (R8): reciprocal-multiply, all correctly-rounded
// f32, half-even rounding, clip to [0,255].
__device__ __forceinline__ int route_of(float cx, float cy, float xmin,
                                        float ymin, float invx, float invy) {
    const float nx = __fmul_rn(__fsub_rn(cx, xmin), invx);
    const float ny = __fmul_rn(__fsub_rn(cy, ymin), invy);
    int px = (int)rintf(__fmul_rn(nx, 255.0f));
    int py = (int)rintf(__fmul_rn(ny, 255.0f));
    px = px < 0 ? 0 : (px > 255 ? 255 : px);
    py = py < 0 ? 0 : (py > 255 ? 255 : py);
    return py * WW + px;
}

// ---------- Kernel B: route table (fast path) ----------
__global__ __launch_bounds__(256) void route_kernel(
    const float2* __restrict__ coords, const float4* __restrict__ partials,
    unsigned short* __restrict__ routes, unsigned int* __restrict__ ovf_count,
    unsigned int* __restrict__ ovf_entries) {
    const int b   = blockIdx.y;
    const int tid = threadIdx.x;
    __shared__ float4 sbox;
    const float4 box = fold_box(partials, b, tid, &sbox);
    const float xmin = box.x, xmax = box.y, ymin = box.z, ymax = box.w;
    const float invx = __fdiv_rn(1.0f, __fsub_rn(xmax, xmin));
    const float invy = __fdiv_rn(1.0f, __fsub_rn(ymax, ymin));

    const int s0 = (blockIdx.x * 256 + tid) * 4;
    unsigned short r4[4];
#pragma unroll
    for (int k = 0; k < 4; k++) {
        const float2 c = coords[s0 + k];
        unsigned short route = 0xFFFFu;  // sentinel: skip
        if (!(c.x < xmin || c.x > xmax || c.y < ymin || c.y > ymax)) {
            const int idx = route_of(c.x, c.y, xmin, ymin, invx, invy);
            if (idx == 0xFFFF) {
                // true corner hit collides with sentinel -> overflow list
                unsigned int pos = atomicAdd(ovf_count, 1u);
                if (pos < OVF_CAP)
                    ovf_entries[pos] = ((unsigned int)b << 18) | (unsigned int)(s0 + k);
            } else {
                route = (unsigned short)idx;
            }
        }
        r4[k] = route;
    }
    *(ushort4*)(routes + (size_t)b * NSRC + s0) =
        make_ushort4(r4[0], r4[1], r4[2], r4[3]);
}

// ---------- Kernel C: banded LDS accumulate (fast path) ----------
__global__ __launch_bounds__(512) void accum_kernel(
    const float* __restrict__ point_rates, const float* __restrict__ gia,
    const unsigned short* __restrict__ routes, float* __restrict__ out) {
    __shared__ float acc[BAND_PIX];
    const int z   = blockIdx.x;   // band
    const int b   = blockIdx.y;   // batch
    const int tid = threadIdx.x;  // 0..511

    for (int j = tid; j < BAND_PIX; j += 512) acc[j] = 0.f;
    __syncthreads();

    const float* prb = point_rates + (size_t)b * NSRC;
    const float* gb  = gia + (size_t)b * HW;
    const uint4* rt4 = (const uint4*)(routes + (size_t)b * NSRC);  // 8 routes/load
    const unsigned int zbits = (unsigned int)z << 13;

#pragma unroll 2
    for (int it = 0; it < NSRC / 8 / 512; ++it) {  // 64 iters
        const int i4 = it * 512 + tid;
        const uint4 w = rt4[i4];
        const int base = i4 * 8;
#define DO_ROUTE(word, sh, off)                                          \
        {                                                                \
            const unsigned int r = ((word) >> (sh)) & 0xFFFFu;           \
            if ((r & 0xE000u) == zbits && r != 0xFFFFu) {                \
                const float em = __fmul_rn(prb[base + (off)], gb[r]);    \
                atomicAdd(&acc[r & 0x1FFFu], em);                        \
            }                                                            \
        }
        DO_ROUTE(w.x, 0, 0) DO_ROUTE(w.x, 16, 1)
        DO_ROUTE(w.y, 0, 2) DO_ROUTE(w.y, 16, 3)
        DO_ROUTE(w.z, 0, 4) DO_ROUTE(w.z, 16, 5)
        DO_ROUTE(w.w, 0, 6) DO_ROUTE(w.w, 16, 7)
#undef DO_ROUTE
    }
    __syncthreads();

    float4* o4 = (float4*)(out + (size_t)b * HW + (size_t)z * BAND_PIX);
    const float4* a4 = (const float4*)acc;
    for (int j = tid; j < BAND_PIX / 4; j += 512) o4[j] = a4[j];
}

// ---------- Kernel D: apply overflow (corner-pixel) entries ----------
__global__ void overflow_kernel(const float* __restrict__ point_rates,
                                const float* __restrict__ gia,
                                const unsigned int* __restrict__ ovf_count,
                                const unsigned int* __restrict__ ovf_entries,
                                float* __restrict__ out) {
    unsigned int n = *ovf_count;
    if (n > OVF_CAP) n = OVF_CAP;
    for (unsigned int j = threadIdx.x; j < n; j += 256) {
        const unsigned int e = ovf_entries[j];
        const int b = e >> 18;
        const int i = e & 0x3FFFF;
        const float em = __fmul_rn(point_rates[(size_t)b * NSRC + i],
                                   gia[(size_t)b * HW + (HW - 1)]);
        atomicAdd(&out[(size_t)b * HW + (HW - 1)], em);
    }
}

// ---------- Fallback: banded accumulate recomputing routes (small ws) ----------
__global__ __launch_bounds__(512) void accum_recompute_kernel(
    const float* __restrict__ point_rates, const float* __restrict__ gia,
    const float2* __restrict__ coords, const float4* __restrict__ partials,
    float* __restrict__ out) {
    __shared__ float acc[BAND_PIX];
    __shared__ float4 sbox;
    const int z   = blockIdx.x;
    const int b   = blockIdx.y;
    const int tid = threadIdx.x;

    const float4 box = fold_box(partials, b, tid, &sbox);
    const float xmin = box.x, xmax = box.y, ymin = box.z, ymax = box.w;
    const float invx = __fdiv_rn(1.0f, __fsub_rn(xmax, xmin));
    const float invy = __fdiv_rn(1.0f, __fsub_rn(ymax, ymin));

    for (int j = tid; j < BAND_PIX; j += 512) acc[j] = 0.f;
    __syncthreads();

    const float* prb = point_rates + (size_t)b * NSRC;
    const float* gb  = gia + (size_t)b * HW;
    const int lo = z * BAND_PIX, hi = lo + BAND_PIX;

    for (int i = tid; i < NSRC; i += 512) {
        const float2 c = coords[i];
        if (c.x < xmin || c.x > xmax || c.y < ymin || c.y > ymax) continue;
        const int idx = route_of(c.x, c.y, xmin, ymin, invx, invy);
        if (idx < lo || idx >= hi) continue;
        const float em = __fmul_rn(prb[i], gb[idx]);
        atomicAdd(&acc[idx - lo], em);
    }
    __syncthreads();

    float4* o4 = (float4*)(out + (size_t)b * HW + (size_t)z * BAND_PIX);
    const float4* a4 = (const float4*)acc;
    for (int j = tid; j < BAND_PIX / 4; j += 512) o4[j] = a4[j];
}

extern "C" void kernel_launch(void* const* d_in, const int* in_sizes, int n_in,
                              void* d_out, int out_size, void* d_ws, size_t ws_size,
                              hipStream_t stream) {
    const float* point_rates = (const float*)d_in[0];   // (B, NSRC)
    const float* spatial     = (const float*)d_in[1];   // (B, 2, H, W)
    const float* gia         = (const float*)d_in[2];   // (B, H, W)
    const float2* coords     = (const float2*)d_in[3];  // (NSRC, 2)
    float* out = (float*)d_out;                         // (B, 1, H, W)

    char* ws = (char*)d_ws;
    float4* partials = (float4*)ws;
    const bool fast = ws_size >= WS_FAST_BYTES;

    unsigned int* ovf_count = (unsigned int*)(ws + WS_OVF_COUNT_OFF);
    unsigned int* ovf_ent   = (unsigned int*)(ws + WS_OVF_ENT_OFF);
    unsigned short* routes  = (unsigned short*)(ws + WS_ROUTES_OFF);

    box_kernel<<<dim3(NBLK, BATCH), 256, 0, stream>>>(
        spatial, partials, fast ? ovf_count : nullptr, fast ? 1 : 0);

    if (fast) {
        route_kernel<<<dim3(NSRC / (256 * 4), BATCH), 256, 0, stream>>>(
            coords, partials, routes, ovf_count, ovf_ent);
        accum_kernel<<<dim3(NBANDS, BATCH), 512, 0, stream>>>(
            point_rates, gia, routes, out);
        overflow_kernel<<<1, 256, 0, stream>>>(
            point_rates, gia, ovf_count, ovf_ent, out);
    } else {
        accum_recompute_kernel<<<dim3(NBANDS, BATCH), 512, 0, stream>>>(
            point_rates, gia, coords, partials, out);
    }
}

// Round 10
// 230.260 us; speedup vs baseline: 2.1265x; 1.2675x over previous
//
#include <hip/hip_runtime.h>
#include <math.h>

// Problem constants: B=32, N_SOURCES=262144, H=W=256
#define BATCH 32
#define NSRC  262144
#define HH    256
#define WW    256
#define HW    (HH * WW)
#define NBLK  16            // partial-reduce blocks per batch
#define NBANDS 8            // row-bands per image
#define BAND_PIX  (HW / NBANDS)      // 8192 floats = 32 KB LDS
#define ARENA_CAP (NSRC + 32)        // per-batch entry arena (+align slack)
#define OVF_CAP   262144

// ---- binned-path ws layout ----
//   [0, 8192)      float4 partials[BATCH][NBLK]
//   [8192, +1KB)   u32 counts[BATCH*NBANDS]
//   [9216, +1KB)   u32 starts[BATCH*NBANDS]
//   [10240, +1KB)  u32 cursors[BATCH*NBANDS]
//   [12288, ...)   u32 arena[BATCH][ARENA_CAP]  entry = pix13 | bf16(em)<<16
#define WS_COUNTS_OFF  8192
#define WS_STARTS_OFF  9216
#define WS_CURSORS_OFF 10240
#define WS_ARENA_OFF   12288
#define WS_BIN_BYTES   (WS_ARENA_OFF + (size_t)BATCH * ARENA_CAP * 4)

// ---- R9 fallback ws layout ----
#define WS_OVF_COUNT_OFF 8192
#define WS_OVF_ENT_OFF   8448
#define WS_ROUTES_OFF    1057024
#define WS_FAST_BYTES    (WS_ROUTES_OFF + (size_t)BATCH * NSRC * 2)

// ---------- Kernel A: per-batch bounding-box partials (+ zero small tables) ----------
__global__ void box_kernel(const float* __restrict__ spatial,
                           float4* __restrict__ partials,
                           unsigned int* __restrict__ zero_tab,  // may be null
                           int zero_n) {
    const int b   = blockIdx.y;
    const int blk = blockIdx.x;
    const int tid = threadIdx.x;  // 0..255

    if (zero_tab && blk == 0 && b == 0) {
        for (int j = tid; j < zero_n; j += 256) zero_tab[j] = 0u;
    }

    const int chunk = HW / NBLK;  // 4096
    const float* xs = spatial + (size_t)b * 2 * HW + (size_t)blk * chunk;
    const float* ys = xs + HW;

    float xmn = 1e30f, xmx = -1e30f, ymn = 1e30f, ymx = -1e30f;
    const float4* xs4 = (const float4*)xs;
    const float4* ys4 = (const float4*)ys;
#pragma unroll
    for (int k = 0; k < 4; k++) {
        float4 vx = xs4[k * 256 + tid];
        float4 vy = ys4[k * 256 + tid];
        xmn = fminf(xmn, fminf(fminf(vx.x, vx.y), fminf(vx.z, vx.w)));
        xmx = fmaxf(xmx, fmaxf(fmaxf(vx.x, vx.y), fmaxf(vx.z, vx.w)));
        ymn = fminf(ymn, fminf(fminf(vy.x, vy.y), fminf(vy.z, vy.w)));
        ymx = fmaxf(ymx, fmaxf(fmaxf(vy.x, vy.y), fmaxf(vy.z, vy.w)));
    }
#pragma unroll
    for (int off = 32; off > 0; off >>= 1) {
        xmn = fminf(xmn, __shfl_down(xmn, off));
        xmx = fmaxf(xmx, __shfl_down(xmx, off));
        ymn = fminf(ymn, __shfl_down(ymn, off));
        ymx = fmaxf(ymx, __shfl_down(ymx, off));
    }
    __shared__ float4 s[4];
    if ((tid & 63) == 0) s[tid >> 6] = make_float4(xmn, xmx, ymn, ymx);
    __syncthreads();
    if (tid == 0) {
        float4 r = s[0];
#pragma unroll
        for (int wv = 1; wv < 4; wv++) {
            float4 t = s[wv];
            r.x = fminf(r.x, t.x); r.y = fmaxf(r.y, t.y);
            r.z = fminf(r.z, t.z); r.w = fmaxf(r.w, t.w);
        }
        partials[b * NBLK + blk] = r;
    }
}

__device__ __forceinline__ float4 fold_box(const float4* __restrict__ partials,
                                           int b, int tid, float4* sbox) {
    if (tid < 64) {
        float4 p = make_float4(1e30f, -1e30f, 1e30f, -1e30f);
        if (tid < NBLK) p = partials[b * NBLK + tid];
        float xmn = p.x, xmx = p.y, ymn = p.z, ymx = p.w;
#pragma unroll
        for (int off = 8; off > 0; off >>= 1) {
            xmn = fminf(xmn, __shfl_down(xmn, off));
            xmx = fmaxf(xmx, __shfl_down(xmx, off));
            ymn = fminf(ymn, __shfl_down(ymn, off));
            ymx = fmaxf(ymx, __shfl_down(ymx, off));
        }
        if (tid == 0) *sbox = make_float4(xmn, xmx, ymn, ymx);
    }
    __syncthreads();
    return *sbox;
}

// Verified reference pipeline (R8): reciprocal-multiply, correctly-rounded f32,
// half-even rounding, clip to [0,255].
__device__ __forceinline__ int route_of(float cx, float cy, float xmin,
                                        float ymin, float invx, float invy) {
    const float nx = __fmul_rn(__fsub_rn(cx, xmin), invx);
    const float ny = __fmul_rn(__fsub_rn(cy, ymin), invy);
    int px = (int)rintf(__fmul_rn(nx, 255.0f));
    int py = (int)rintf(__fmul_rn(ny, 255.0f));
    px = px < 0 ? 0 : (px > 255 ? 255 : px);
    py = py < 0 ? 0 : (py > 255 ? 255 : py);
    return py * WW + px;
}

// ================= BINNED PATH =================

// ---------- Kernel B1: count sources per (batch, band) ----------
__global__ __launch_bounds__(256) void count_kernel(
    const float2* __restrict__ coords, const float4* __restrict__ partials,
    unsigned int* __restrict__ counts) {
    const int b   = blockIdx.y;
    const int tid = threadIdx.x;
    __shared__ float4 sbox;
    __shared__ unsigned int hist[NBANDS];
    const float4 box = fold_box(partials, b, tid, &sbox);
    const float xmin = box.x, xmax = box.y, ymin = box.z, ymax = box.w;
    const float invx = __fdiv_rn(1.0f, __fsub_rn(xmax, xmin));
    const float invy = __fdiv_rn(1.0f, __fsub_rn(ymax, ymin));
    if (tid < NBANDS) hist[tid] = 0u;
    __syncthreads();

    const int base = blockIdx.x * 4096;
#pragma unroll 4
    for (int k = 0; k < 16; k++) {
        const int i = base + k * 256 + tid;
        const float2 c = coords[i];
        if (c.x < xmin || c.x > xmax || c.y < ymin || c.y > ymax) continue;
        const int idx = route_of(c.x, c.y, xmin, ymin, invx, invy);
        atomicAdd(&hist[idx >> 13], 1u);
    }
    __syncthreads();
    if (tid < NBANDS) atomicAdd(&counts[b * NBANDS + tid], hist[tid]);
}

// ---------- Kernel B2: prefix (bin starts, 16B-aligned) ----------
__global__ void prefix_kernel(const unsigned int* __restrict__ counts,
                              unsigned int* __restrict__ starts,
                              unsigned int* __restrict__ cursors) {
    const int b = threadIdx.x;
    if (b >= BATCH) return;
    unsigned int s = 0;
    for (int z = 0; z < NBANDS; z++) {
        s = (s + 3u) & ~3u;  // align starts to 4 entries (uint4 loads in accum)
        starts[b * NBANDS + z]  = s;
        cursors[b * NBANDS + z] = s;
        s += counts[b * NBANDS + z];
    }
}

// ---------- Kernel B3: scatter compacted entries into bins ----------
__global__ __launch_bounds__(256) void scatter_bin_kernel(
    const float* __restrict__ point_rates, const float* __restrict__ gia,
    const float2* __restrict__ coords, const float4* __restrict__ partials,
    unsigned int* __restrict__ cursors, unsigned int* __restrict__ arena) {
    const int b   = blockIdx.y;
    const int tid = threadIdx.x;
    __shared__ float4 sbox;
    __shared__ unsigned int hist[NBANDS];
    __shared__ unsigned int bbase[NBANDS];
    const float4 box = fold_box(partials, b, tid, &sbox);
    const float xmin = box.x, xmax = box.y, ymin = box.z, ymax = box.w;
    const float invx = __fdiv_rn(1.0f, __fsub_rn(xmax, xmin));
    const float invy = __fdiv_rn(1.0f, __fsub_rn(ymax, ymin));
    if (tid < NBANDS) hist[tid] = 0u;
    __syncthreads();

    const float* prb = point_rates + (size_t)b * NSRC;
    const float* gb  = gia + (size_t)b * HW;
    const int base = blockIdx.x * 4096;

    unsigned int ent[16];
    unsigned short rnk[16];
    unsigned char  bin[16];
#pragma unroll
    for (int k = 0; k < 16; k++) {
        const int i = base + k * 256 + tid;
        const float2 c = coords[i];
        bin[k] = 0xFF;
        if (c.x < xmin || c.x > xmax || c.y < ymin || c.y > ymax) continue;
        const int idx = route_of(c.x, c.y, xmin, ymin, invx, invy);
        const float em = __fmul_rn(prb[i], gb[idx]);
        // f32 -> bf16 round-to-nearest-even (em >= 0, finite)
        const unsigned int bits = __float_as_uint(em);
        const unsigned int b16 = (bits + 0x7FFFu + ((bits >> 16) & 1u)) >> 16;
        const int z = idx >> 13;
        rnk[k] = (unsigned short)atomicAdd(&hist[z], 1u);
        ent[k] = (unsigned int)(idx & 0x1FFF) | (b16 << 16);
        bin[k] = (unsigned char)z;
    }
    __syncthreads();
    if (tid < NBANDS) bbase[tid] = atomicAdd(&cursors[b * NBANDS + tid], hist[tid]);
    __syncthreads();
    unsigned int* ab = arena + (size_t)b * ARENA_CAP;
#pragma unroll
    for (int k = 0; k < 16; k++) {
        if (bin[k] != 0xFF) ab[bbase[bin[k]] + rnk[k]] = ent[k];
    }
}

// ---------- Kernel B4: per-band LDS accumulate from compacted bin ----------
__global__ __launch_bounds__(1024) void accum_bin_kernel(
    const unsigned int* __restrict__ arena,
    const unsigned int* __restrict__ starts,
    const unsigned int* __restrict__ counts, float* __restrict__ out) {
    __shared__ float acc[BAND_PIX];
    const int z   = blockIdx.x;
    const int b   = blockIdx.y;
    const int tid = threadIdx.x;  // 0..1023

#pragma unroll
    for (int j = 0; j < BAND_PIX / 1024; j++) acc[j * 1024 + tid] = 0.f;
    __syncthreads();

    const unsigned int start = starts[b * NBANDS + z];
    const unsigned int n     = counts[b * NBANDS + z];
    const uint4* a4 = (const uint4*)(arena + (size_t)b * ARENA_CAP + start);

    const unsigned int n4 = n >> 2;
    for (unsigned int j = tid; j < n4; j += 1024) {
        const uint4 e = a4[j];
#define DO_E(w)  atomicAdd(&acc[(w) & 0x1FFFu], __uint_as_float((w) & 0xFFFF0000u));
        DO_E(e.x) DO_E(e.y) DO_E(e.z) DO_E(e.w)
    }
    // tail
    const unsigned int* a1 = (const unsigned int*)a4;
    for (unsigned int j = (n4 << 2) + tid; j < n; j += 1024) {
        const unsigned int w = a1[j];
        DO_E(w)
    }
#undef DO_E
    __syncthreads();

    float4* o4 = (float4*)(out + (size_t)b * HW + (size_t)z * BAND_PIX);
    const float4* c4 = (const float4*)acc;
#pragma unroll
    for (int j = 0; j < BAND_PIX / 4 / 1024; j++) o4[j * 1024 + tid] = c4[j * 1024 + tid];
}

// ================= R9 FALLBACK PATH (route table) =================

__global__ __launch_bounds__(256) void route_kernel(
    const float2* __restrict__ coords, const float4* __restrict__ partials,
    unsigned short* __restrict__ routes, unsigned int* __restrict__ ovf_count,
    unsigned int* __restrict__ ovf_entries) {
    const int b   = blockIdx.y;
    const int tid = threadIdx.x;
    __shared__ float4 sbox;
    const float4 box = fold_box(partials, b, tid, &sbox);
    const float xmin = box.x, xmax = box.y, ymin = box.z, ymax = box.w;
    const float invx = __fdiv_rn(1.0f, __fsub_rn(xmax, xmin));
    const float invy = __fdiv_rn(1.0f, __fsub_rn(ymax, ymin));

    const int s0 = (blockIdx.x * 256 + tid) * 4;
    unsigned short r4[4];
#pragma unroll
    for (int k = 0; k < 4; k++) {
        const float2 c = coords[s0 + k];
        unsigned short route = 0xFFFFu;
        if (!(c.x < xmin || c.x > xmax || c.y < ymin || c.y > ymax)) {
            const int idx = route_of(c.x, c.y, xmin, ymin, invx, invy);
            if (idx == 0xFFFF) {
                unsigned int pos = atomicAdd(ovf_count, 1u);
                if (pos < OVF_CAP)
                    ovf_entries[pos] = ((unsigned int)b << 18) | (unsigned int)(s0 + k);
            } else {
                route = (unsigned short)idx;
            }
        }
        r4[k] = route;
    }
    *(ushort4*)(routes + (size_t)b * NSRC + s0) =
        make_ushort4(r4[0], r4[1], r4[2], r4[3]);
}

__global__ __launch_bounds__(512) void accum_kernel(
    const float* __restrict__ point_rates, const float* __restrict__ gia,
    const unsigned short* __restrict__ routes, float* __restrict__ out) {
    __shared__ float acc[BAND_PIX];
    const int z   = blockIdx.x;
    const int b   = blockIdx.y;
    const int tid = threadIdx.x;

    for (int j = tid; j < BAND_PIX; j += 512) acc[j] = 0.f;
    __syncthreads();

    const float* prb = point_rates + (size_t)b * NSRC;
    const float* gb  = gia + (size_t)b * HW;
    const uint4* rt4 = (const uint4*)(routes + (size_t)b * NSRC);
    const unsigned int zbits = (unsigned int)z << 13;

#pragma unroll 2
    for (int it = 0; it < NSRC / 8 / 512; ++it) {
        const int i4 = it * 512 + tid;
        const uint4 w = rt4[i4];
        const int base = i4 * 8;
#define DO_ROUTE(word, sh, off)                                          \
        {                                                                \
            const unsigned int r = ((word) >> (sh)) & 0xFFFFu;           \
            if ((r & 0xE000u) == zbits && r != 0xFFFFu) {                \
                const float em = __fmul_rn(prb[base + (off)], gb[r]);    \
                atomicAdd(&acc[r & 0x1FFFu], em);                        \
            }                                                            \
        }
        DO_ROUTE(w.x, 0, 0) DO_ROUTE(w.x, 16, 1)
        DO_ROUTE(w.y, 0, 2) DO_ROUTE(w.y, 16, 3)
        DO_ROUTE(w.z, 0, 4) DO_ROUTE(w.z, 16, 5)
        DO_ROUTE(w.w, 0, 6) DO_ROUTE(w.w, 16, 7)
#undef DO_ROUTE
    }
    __syncthreads();

    float4* o4 = (float4*)(out + (size_t)b * HW + (size_t)z * BAND_PIX);
    const float4* a4 = (const float4*)acc;
    for (int j = tid; j < BAND_PIX / 4; j += 512) o4[j] = a4[j];
}

__global__ void overflow_kernel(const float* __restrict__ point_rates,
                                const float* __restrict__ gia,
                                const unsigned int* __restrict__ ovf_count,
                                const unsigned int* __restrict__ ovf_entries,
                                float* __restrict__ out) {
    unsigned int n = *ovf_count;
    if (n > OVF_CAP) n = OVF_CAP;
    for (unsigned int j = threadIdx.x; j < n; j += 256) {
        const unsigned int e = ovf_entries[j];
        const int b = e >> 18;
        const int i = e & 0x3FFFF;
        const float em = __fmul_rn(point_rates[(size_t)b * NSRC + i],
                                   gia[(size_t)b * HW + (HW - 1)]);
        atomicAdd(&out[(size_t)b * HW + (HW - 1)], em);
    }
}

__global__ __launch_bounds__(512) void accum_recompute_kernel(
    const float* __restrict__ point_rates, const float* __restrict__ gia,
    const float2* __restrict__ coords, const float4* __restrict__ partials,
    float* __restrict__ out) {
    __shared__ float acc[BAND_PIX];
    __shared__ float4 sbox;
    const int z   = blockIdx.x;
    const int b   = blockIdx.y;
    const int tid = threadIdx.x;

    const float4 box = fold_box(partials, b, tid, &sbox);
    const float xmin = box.x, xmax = box.y, ymin = box.z, ymax = box.w;
    const float invx = __fdiv_rn(1.0f, __fsub_rn(xmax, xmin));
    const float invy = __fdiv_rn(1.0f, __fsub_rn(ymax, ymin));

    for (int j = tid; j < BAND_PIX; j += 512) acc[j] = 0.f;
    __syncthreads();

    const float* prb = point_rates + (size_t)b * NSRC;
    const float* gb  = gia + (size_t)b * HW;
    const int lo = z * BAND_PIX, hi = lo + BAND_PIX;

    for (int i = tid; i < NSRC; i += 512) {
        const float2 c = coords[i];
        if (c.x < xmin || c.x > xmax || c.y < ymin || c.y > ymax) continue;
        const int idx = route_of(c.x, c.y, xmin, ymin, invx, invy);
        if (idx < lo || idx >= hi) continue;
        const float em = __fmul_rn(prb[i], gb[idx]);
        atomicAdd(&acc[idx - lo], em);
    }
    __syncthreads();

    float4* o4 = (float4*)(out + (size_t)b * HW + (size_t)z * BAND_PIX);
    const float4* a4 = (const float4*)acc;
    for (int j = tid; j < BAND_PIX / 4; j += 512) o4[j] = a4[j];
}

extern "C" void kernel_launch(void* const* d_in, const int* in_sizes, int n_in,
                              void* d_out, int out_size, void* d_ws, size_t ws_size,
                              hipStream_t stream) {
    const float* point_rates = (const float*)d_in[0];   // (B, NSRC)
    const float* spatial     = (const float*)d_in[1];   // (B, 2, H, W)
    const float* gia         = (const float*)d_in[2];   // (B, H, W)
    const float2* coords     = (const float2*)d_in[3];  // (NSRC, 2)
    float* out = (float*)d_out;                         // (B, 1, H, W)

    char* ws = (char*)d_ws;
    float4* partials = (float4*)ws;

    if (ws_size >= WS_BIN_BYTES) {
        unsigned int* counts  = (unsigned int*)(ws + WS_COUNTS_OFF);
        unsigned int* starts  = (unsigned int*)(ws + WS_STARTS_OFF);
        unsigned int* cursors = (unsigned int*)(ws + WS_CURSORS_OFF);
        unsigned int* arena   = (unsigned int*)(ws + WS_ARENA_OFF);

        box_kernel<<<dim3(NBLK, BATCH), 256, 0, stream>>>(
            spatial, partials, counts, BATCH * NBANDS);
        count_kernel<<<dim3(NSRC / 4096, BATCH), 256, 0, stream>>>(
            coords, partials, counts);
        prefix_kernel<<<1, 64, 0, stream>>>(counts, starts, cursors);
        scatter_bin_kernel<<<dim3(NSRC / 4096, BATCH), 256, 0, stream>>>(
            point_rates, gia, coords, partials, cursors, arena);
        accum_bin_kernel<<<dim3(NBANDS, BATCH), 1024, 0, stream>>>(
            arena, starts, counts, out);
    } else if (ws_size >= WS_FAST_BYTES) {
        unsigned int* ovf_count = (unsigned int*)(ws + WS_OVF_COUNT_OFF);
        unsigned int* ovf_ent   = (unsigned int*)(ws + WS_OVF_ENT_OFF);
        unsigned short* routes  = (unsigned short*)(ws + WS_ROUTES_OFF);

        box_kernel<<<dim3(NBLK, BATCH), 256, 0, stream>>>(
            spatial, partials, ovf_count, 1);
        route_kernel<<<dim3(NSRC / (256 * 4), BATCH), 256, 0, stream>>>(
            coords, partials, routes, ovf_count, ovf_ent);
        accum_kernel<<<dim3(NBANDS, BATCH), 512, 0, stream>>>(
            point_rates, gia, routes, out);
        overflow_kernel<<<1, 256, 0, stream>>>(
            point_rates, gia, ovf_count, ovf_ent, out);
    } else {
        box_kernel<<<dim3(NBLK, BATCH), 256, 0, stream>>>(
            spatial, partials, nullptr, 0);
        accum_recompute_kernel<<<dim3(NBANDS, BATCH), 512, 0, stream>>>(
            point_rates, gia, coords, partials, out);
    }
}

// Round 11
// 178.347 us; speedup vs baseline: 2.7455x; 1.2911x over previous
//
#include <hip/hip_runtime.h>
#include <math.h>

// Problem constants: B=32, N_SOURCES=262144, H=W=256
#define BATCH 32
#define NSRC  262144
#define HH    256
#define WW    256
#define HW    (HH * WW)
#define NBLK  16                 // partial-reduce blocks per batch
#define NBANDS 16                // row-bands per image (16 rows each)
#define BAND_PIX  (HW / NBANDS)  // 4096 floats = 16 KB LDS
#define ARENA_CAP (NSRC + 48)    // per-batch entries + alignment pad (16 bins x 3)
#define OVF_CAP   262144

// ---- binned-path ws layout ----
//   [0, 8192)      float4 partials[BATCH][NBLK]
//   [8192, +2KB)   u32 counts[BATCH*NBANDS]        (512)
//   [10240, +2KB)  u32 cursors_rel[BATCH*NBANDS]   (512)
//   [12288, ...)   u32 arena[BATCH][ARENA_CAP]  entry = pix12 | bf16(pr)<<16
#define WS_COUNTS_OFF  8192
#define WS_CURSORS_OFF 10240
#define WS_ARENA_OFF   12288
#define WS_BIN_BYTES   (WS_ARENA_OFF + (size_t)BATCH * ARENA_CAP * 4)

// ---- R9 fallback ws layout ----
#define WS_OVF_COUNT_OFF 8192
#define WS_OVF_ENT_OFF   8448
#define WS_ROUTES_OFF    1057024
#define WS_FAST_BYTES    (WS_ROUTES_OFF + (size_t)BATCH * NSRC * 2)
#define FB_BANDS 8
#define FB_BAND_PIX (HW / FB_BANDS)

// ---------- Kernel A: per-batch bounding-box partials (+ zero small tables) ----------
__global__ void box_kernel(const float* __restrict__ spatial,
                           float4* __restrict__ partials,
                           unsigned int* __restrict__ zero_tab,  // may be null
                           int zero_n) {
    const int b   = blockIdx.y;
    const int blk = blockIdx.x;
    const int tid = threadIdx.x;  // 0..255

    if (zero_tab && blk == 0 && b == 0) {
        for (int j = tid; j < zero_n; j += 256) zero_tab[j] = 0u;
    }

    const int chunk = HW / NBLK;  // 4096
    const float* xs = spatial + (size_t)b * 2 * HW + (size_t)blk * chunk;
    const float* ys = xs + HW;

    float xmn = 1e30f, xmx = -1e30f, ymn = 1e30f, ymx = -1e30f;
    const float4* xs4 = (const float4*)xs;
    const float4* ys4 = (const float4*)ys;
#pragma unroll
    for (int k = 0; k < 4; k++) {
        float4 vx = xs4[k * 256 + tid];
        float4 vy = ys4[k * 256 + tid];
        xmn = fminf(xmn, fminf(fminf(vx.x, vx.y), fminf(vx.z, vx.w)));
        xmx = fmaxf(xmx, fmaxf(fmaxf(vx.x, vx.y), fmaxf(vx.z, vx.w)));
        ymn = fminf(ymn, fminf(fminf(vy.x, vy.y), fminf(vy.z, vy.w)));
        ymx = fmaxf(ymx, fmaxf(fmaxf(vy.x, vy.y), fmaxf(vy.z, vy.w)));
    }
#pragma unroll
    for (int off = 32; off > 0; off >>= 1) {
        xmn = fminf(xmn, __shfl_down(xmn, off));
        xmx = fmaxf(xmx, __shfl_down(xmx, off));
        ymn = fminf(ymn, __shfl_down(ymn, off));
        ymx = fmaxf(ymx, __shfl_down(ymx, off));
    }
    __shared__ float4 s[4];
    if ((tid & 63) == 0) s[tid >> 6] = make_float4(xmn, xmx, ymn, ymx);
    __syncthreads();
    if (tid == 0) {
        float4 r = s[0];
#pragma unroll
        for (int wv = 1; wv < 4; wv++) {
            float4 t = s[wv];
            r.x = fminf(r.x, t.x); r.y = fmaxf(r.y, t.y);
            r.z = fminf(r.z, t.z); r.w = fmaxf(r.w, t.w);
        }
        partials[b * NBLK + blk] = r;
    }
}

__device__ __forceinline__ float4 fold_box(const float4* __restrict__ partials,
                                           int b, int tid, float4* sbox) {
    if (tid < 64) {
        float4 p = make_float4(1e30f, -1e30f, 1e30f, -1e30f);
        if (tid < NBLK) p = partials[b * NBLK + tid];
        float xmn = p.x, xmx = p.y, ymn = p.z, ymx = p.w;
#pragma unroll
        for (int off = 8; off > 0; off >>= 1) {
            xmn = fminf(xmn, __shfl_down(xmn, off));
            xmx = fmaxf(xmx, __shfl_down(xmx, off));
            ymn = fminf(ymn, __shfl_down(ymn, off));
            ymx = fmaxf(ymx, __shfl_down(ymx, off));
        }
        if (tid == 0) *sbox = make_float4(xmn, xmx, ymn, ymx);
    }
    __syncthreads();
    return *sbox;
}

// Verified reference pipeline (R8): reciprocal-multiply, correctly-rounded f32,
// half-even rounding, clip to [0,255].
__device__ __forceinline__ int route_of(float cx, float cy, float xmin,
                                        float ymin, float invx, float invy) {
    const float nx = __fmul_rn(__fsub_rn(cx, xmin), invx);
    const float ny = __fmul_rn(__fsub_rn(cy, ymin), invy);
    int px = (int)rintf(__fmul_rn(nx, 255.0f));
    int py = (int)rintf(__fmul_rn(ny, 255.0f));
    px = px < 0 ? 0 : (px > 255 ? 255 : px);
    py = py < 0 ? 0 : (py > 255 ? 255 : py);
    return py * WW + px;
}

// Per-batch aligned bin starts from counts (serial over 16 bins, one lane).
__device__ __forceinline__ void compute_starts(const unsigned int* __restrict__ counts,
                                               int b, int tid,
                                               unsigned int* sstarts) {
    if (tid == 0) {
        unsigned int s = 0;
        for (int z = 0; z < NBANDS; z++) {
            s = (s + 3u) & ~3u;  // 16B-align each bin for uint4 loads
            sstarts[z] = s;
            s += counts[b * NBANDS + z];
        }
    }
    __syncthreads();
}

// ================= BINNED PATH =================

// ---------- Kernel B1: count sources per (batch, band) ----------
__global__ __launch_bounds__(256) void count_kernel(
    const float2* __restrict__ coords, const float4* __restrict__ partials,
    unsigned int* __restrict__ counts) {
    const int b   = blockIdx.y;
    const int tid = threadIdx.x;
    __shared__ float4 sbox;
    __shared__ unsigned int hist[NBANDS];
    const float4 box = fold_box(partials, b, tid, &sbox);
    const float xmin = box.x, xmax = box.y, ymin = box.z, ymax = box.w;
    const float invx = __fdiv_rn(1.0f, __fsub_rn(xmax, xmin));
    const float invy = __fdiv_rn(1.0f, __fsub_rn(ymax, ymin));
    if (tid < NBANDS) hist[tid] = 0u;
    __syncthreads();

    const int base = blockIdx.x * 4096;
#pragma unroll 4
    for (int k = 0; k < 16; k++) {
        const int i = base + k * 256 + tid;
        const float2 c = coords[i];
        if (c.x < xmin || c.x > xmax || c.y < ymin || c.y > ymax) continue;
        const int idx = route_of(c.x, c.y, xmin, ymin, invx, invy);
        atomicAdd(&hist[idx / BAND_PIX], 1u);
    }
    __syncthreads();
    if (tid < NBANDS) atomicAdd(&counts[b * NBANDS + tid], hist[tid]);
}

// ---------- Kernel B2: scatter compacted entries (pix | bf16(pr)) into bins ----------
__global__ __launch_bounds__(256) void scatter_bin_kernel(
    const float* __restrict__ point_rates, const float2* __restrict__ coords,
    const float4* __restrict__ partials, const unsigned int* __restrict__ counts,
    unsigned int* __restrict__ cursors, unsigned int* __restrict__ arena) {
    const int b   = blockIdx.y;
    const int tid = threadIdx.x;
    __shared__ float4 sbox;
    __shared__ unsigned int sstarts[NBANDS];
    __shared__ unsigned int hist[NBANDS];
    __shared__ unsigned int bbase[NBANDS];
    const float4 box = fold_box(partials, b, tid, &sbox);
    compute_starts(counts, b, tid, sstarts);
    const float xmin = box.x, xmax = box.y, ymin = box.z, ymax = box.w;
    const float invx = __fdiv_rn(1.0f, __fsub_rn(xmax, xmin));
    const float invy = __fdiv_rn(1.0f, __fsub_rn(ymax, ymin));
    if (tid < NBANDS) hist[tid] = 0u;
    __syncthreads();

    const float* prb = point_rates + (size_t)b * NSRC;
    const int base = blockIdx.x * 4096;

    unsigned int ent[16];
    unsigned short rnk[16];
    unsigned char  bin[16];
#pragma unroll
    for (int k = 0; k < 16; k++) {
        const int i = base + k * 256 + tid;
        const float2 c = coords[i];
        bin[k] = 0xFF;
        if (c.x < xmin || c.x > xmax || c.y < ymin || c.y > ymax) continue;
        const int idx = route_of(c.x, c.y, xmin, ymin, invx, invy);
        // f32 -> bf16 RNE of point_rate (>=0, finite); gia multiply deferred
        // to the accumulate pass where gia's band lives in LDS.
        const unsigned int bits = __float_as_uint(prb[i]);
        const unsigned int b16 = (bits + 0x7FFFu + ((bits >> 16) & 1u)) >> 16;
        const int z = idx / BAND_PIX;
        rnk[k] = (unsigned short)atomicAdd(&hist[z], 1u);
        ent[k] = (unsigned int)(idx & (BAND_PIX - 1)) | (b16 << 16);
        bin[k] = (unsigned char)z;
    }
    __syncthreads();
    if (tid < NBANDS)
        bbase[tid] = sstarts[tid] + atomicAdd(&cursors[b * NBANDS + tid], hist[tid]);
    __syncthreads();
    unsigned int* ab = arena + (size_t)b * ARENA_CAP;
#pragma unroll
    for (int k = 0; k < 16; k++) {
        if (bin[k] != 0xFF) ab[bbase[bin[k]] + rnk[k]] = ent[k];
    }
}

// ---------- Kernel B3: per-band accumulate; gia band staged in LDS ----------
__global__ __launch_bounds__(512) void accum_bin_kernel(
    const unsigned int* __restrict__ arena, const float* __restrict__ gia,
    const unsigned int* __restrict__ counts, float* __restrict__ out) {
    __shared__ float acc[BAND_PIX];
    __shared__ float gld[BAND_PIX];
    __shared__ unsigned int sstarts[NBANDS];
    const int z   = blockIdx.x;
    const int b   = blockIdx.y;
    const int tid = threadIdx.x;  // 0..511

    compute_starts(counts, b, tid, sstarts);

    const float4* g4 = (const float4*)(gia + (size_t)b * HW + (size_t)z * BAND_PIX);
    float4* gl4 = (float4*)gld;
#pragma unroll
    for (int j = 0; j < BAND_PIX / 4 / 512; j++) gl4[j * 512 + tid] = g4[j * 512 + tid];
#pragma unroll
    for (int j = 0; j < BAND_PIX / 512; j++) acc[j * 512 + tid] = 0.f;
    __syncthreads();

    const unsigned int start = sstarts[z];
    const unsigned int n     = counts[b * NBANDS + z];
    const uint4* a4 = (const uint4*)(arena + (size_t)b * ARENA_CAP + start);

    const unsigned int n4 = n >> 2;
    for (unsigned int j = tid; j < n4; j += 512) {
        const uint4 e = a4[j];
#define DO_E(w)                                                              \
        atomicAdd(&acc[(w) & (BAND_PIX - 1)],                                \
                  __fmul_rn(__uint_as_float((w) & 0xFFFF0000u),              \
                            gld[(w) & (BAND_PIX - 1)]));
        DO_E(e.x) DO_E(e.y) DO_E(e.z) DO_E(e.w)
    }
    const unsigned int* a1 = (const unsigned int*)a4;
    for (unsigned int j = (n4 << 2) + tid; j < n; j += 512) {
        const unsigned int w = a1[j];
        DO_E(w)
    }
#undef DO_E
    __syncthreads();

    float4* o4 = (float4*)(out + (size_t)b * HW + (size_t)z * BAND_PIX);
    const float4* c4 = (const float4*)acc;
#pragma unroll
    for (int j = 0; j < BAND_PIX / 4 / 512; j++) o4[j * 512 + tid] = c4[j * 512 + tid];
}

// ================= R9 FALLBACK PATH (route table) =================

__global__ __launch_bounds__(256) void route_kernel(
    const float2* __restrict__ coords, const float4* __restrict__ partials,
    unsigned short* __restrict__ routes, unsigned int* __restrict__ ovf_count,
    unsigned int* __restrict__ ovf_entries) {
    const int b   = blockIdx.y;
    const int tid = threadIdx.x;
    __shared__ float4 sbox;
    const float4 box = fold_box(partials, b, tid, &sbox);
    const float xmin = box.x, xmax = box.y, ymin = box.z, ymax = box.w;
    const float invx = __fdiv_rn(1.0f, __fsub_rn(xmax, xmin));
    const float invy = __fdiv_rn(1.0f, __fsub_rn(ymax, ymin));

    const int s0 = (blockIdx.x * 256 + tid) * 4;
    unsigned short r4[4];
#pragma unroll
    for (int k = 0; k < 4; k++) {
        const float2 c = coords[s0 + k];
        unsigned short route = 0xFFFFu;
        if (!(c.x < xmin || c.x > xmax || c.y < ymin || c.y > ymax)) {
            const int idx = route_of(c.x, c.y, xmin, ymin, invx, invy);
            if (idx == 0xFFFF) {
                unsigned int pos = atomicAdd(ovf_count, 1u);
                if (pos < OVF_CAP)
                    ovf_entries[pos] = ((unsigned int)b << 18) | (unsigned int)(s0 + k);
            } else {
                route = (unsigned short)idx;
            }
        }
        r4[k] = route;
    }
    *(ushort4*)(routes + (size_t)b * NSRC + s0) =
        make_ushort4(r4[0], r4[1], r4[2], r4[3]);
}

__global__ __launch_bounds__(512) void accum_kernel(
    const float* __restrict__ point_rates, const float* __restrict__ gia,
    const unsigned short* __restrict__ routes, float* __restrict__ out) {
    __shared__ float acc[FB_BAND_PIX];
    const int z   = blockIdx.x;
    const int b   = blockIdx.y;
    const int tid = threadIdx.x;

    for (int j = tid; j < FB_BAND_PIX; j += 512) acc[j] = 0.f;
    __syncthreads();

    const float* prb = point_rates + (size_t)b * NSRC;
    const float* gb  = gia + (size_t)b * HW;
    const uint4* rt4 = (const uint4*)(routes + (size_t)b * NSRC);
    const unsigned int zbits = (unsigned int)z << 13;

#pragma unroll 2
    for (int it = 0; it < NSRC / 8 / 512; ++it) {
        const int i4 = it * 512 + tid;
        const uint4 w = rt4[i4];
        const int base = i4 * 8;
#define DO_ROUTE(word, sh, off)                                          \
        {                                                                \
            const unsigned int r = ((word) >> (sh)) & 0xFFFFu;           \
            if ((r & 0xE000u) == zbits && r != 0xFFFFu) {                \
                const float em = __fmul_rn(prb[base + (off)], gb[r]);    \
                atomicAdd(&acc[r & 0x1FFFu], em);                        \
            }                                                            \
        }
        DO_ROUTE(w.x, 0, 0) DO_ROUTE(w.x, 16, 1)
        DO_ROUTE(w.y, 0, 2) DO_ROUTE(w.y, 16, 3)
        DO_ROUTE(w.z, 0, 4) DO_ROUTE(w.z, 16, 5)
        DO_ROUTE(w.w, 0, 6) DO_ROUTE(w.w, 16, 7)
#undef DO_ROUTE
    }
    __syncthreads();

    float4* o4 = (float4*)(out + (size_t)b * HW + (size_t)z * FB_BAND_PIX);
    const float4* a4 = (const float4*)acc;
    for (int j = tid; j < FB_BAND_PIX / 4; j += 512) o4[j] = a4[j];
}

__global__ void overflow_kernel(const float* __restrict__ point_rates,
                                const float* __restrict__ gia,
                                const unsigned int* __restrict__ ovf_count,
                                const unsigned int* __restrict__ ovf_entries,
                                float* __restrict__ out) {
    unsigned int n = *ovf_count;
    if (n > OVF_CAP) n = OVF_CAP;
    for (unsigned int j = threadIdx.x; j < n; j += 256) {
        const unsigned int e = ovf_entries[j];
        const int b = e >> 18;
        const int i = e & 0x3FFFF;
        const float em = __fmul_rn(point_rates[(size_t)b * NSRC + i],
                                   gia[(size_t)b * HW + (HW - 1)]);
        atomicAdd(&out[(size_t)b * HW + (HW - 1)], em);
    }
}

__global__ __launch_bounds__(512) void accum_recompute_kernel(
    const float* __restrict__ point_rates, const float* __restrict__ gia,
    const float2* __restrict__ coords, const float4* __restrict__ partials,
    float* __restrict__ out) {
    __shared__ float acc[FB_BAND_PIX];
    __shared__ float4 sbox;
    const int z   = blockIdx.x;
    const int b   = blockIdx.y;
    const int tid = threadIdx.x;

    const float4 box = fold_box(partials, b, tid, &sbox);
    const float xmin = box.x, xmax = box.y, ymin = box.z, ymax = box.w;
    const float invx = __fdiv_rn(1.0f, __fsub_rn(xmax, xmin));
    const float invy = __fdiv_rn(1.0f, __fsub_rn(ymax, ymin));

    for (int j = tid; j < FB_BAND_PIX; j += 512) acc[j] = 0.f;
    __syncthreads();

    const float* prb = point_rates + (size_t)b * NSRC;
    const float* gb  = gia + (size_t)b * HW;
    const int lo = z * FB_BAND_PIX, hi = lo + FB_BAND_PIX;

    for (int i = tid; i < NSRC; i += 512) {
        const float2 c = coords[i];
        if (c.x < xmin || c.x > xmax || c.y < ymin || c.y > ymax) continue;
        const int idx = route_of(c.x, c.y, xmin, ymin, invx, invy);
        if (idx < lo || idx >= hi) continue;
        const float em = __fmul_rn(prb[i], gb[idx]);
        atomicAdd(&acc[idx - lo], em);
    }
    __syncthreads();

    float4* o4 = (float4*)(out + (size_t)b * HW + (size_t)z * FB_BAND_PIX);
    const float4* a4 = (const float4*)acc;
    for (int j = tid; j < FB_BAND_PIX / 4; j += 512) o4[j] = a4[j];
}

extern "C" void kernel_launch(void* const* d_in, const int* in_sizes, int n_in,
                              void* d_out, int out_size, void* d_ws, size_t ws_size,
                              hipStream_t stream) {
    const float* point_rates = (const float*)d_in[0];   // (B, NSRC)
    const float* spatial     = (const float*)d_in[1];   // (B, 2, H, W)
    const float* gia         = (const float*)d_in[2];   // (B, H, W)
    const float2* coords     = (const float2*)d_in[3];  // (NSRC, 2)
    float* out = (float*)d_out;                         // (B, 1, H, W)

    char* ws = (char*)d_ws;
    float4* partials = (float4*)ws;

    if (ws_size >= WS_BIN_BYTES) {
        unsigned int* counts  = (unsigned int*)(ws + WS_COUNTS_OFF);
        unsigned int* cursors = (unsigned int*)(ws + WS_CURSORS_OFF);
        unsigned int* arena   = (unsigned int*)(ws + WS_ARENA_OFF);

        // counts+cursors are contiguous: zero both (1024 u32) in box_kernel
        box_kernel<<<dim3(NBLK, BATCH), 256, 0, stream>>>(
            spatial, partials, counts, 2 * BATCH * NBANDS + 512 / 4);
        count_kernel<<<dim3(NSRC / 4096, BATCH), 256, 0, stream>>>(
            coords, partials, counts);
        scatter_bin_kernel<<<dim3(NSRC / 4096, BATCH), 256, 0, stream>>>(
            point_rates, coords, partials, counts, cursors, arena);
        accum_bin_kernel<<<dim3(NBANDS, BATCH), 512, 0, stream>>>(
            arena, gia, counts, out);
    } else if (ws_size >= WS_FAST_BYTES) {
        unsigned int* ovf_count = (unsigned int*)(ws + WS_OVF_COUNT_OFF);
        unsigned int* ovf_ent   = (unsigned int*)(ws + WS_OVF_ENT_OFF);
        unsigned short* routes  = (unsigned short*)(ws + WS_ROUTES_OFF);

        box_kernel<<<dim3(NBLK, BATCH), 256, 0, stream>>>(
            spatial, partials, ovf_count, 1);
        route_kernel<<<dim3(NSRC / (256 * 4), BATCH), 256, 0, stream>>>(
            coords, partials, routes, ovf_count, ovf_ent);
        accum_kernel<<<dim3(FB_BANDS, BATCH), 512, 0, stream>>>(
            point_rates, gia, routes, out);
        overflow_kernel<<<1, 256, 0, stream>>>(
            point_rates, gia, ovf_count, ovf_ent, out);
    } else {
        box_kernel<<<dim3(NBLK, BATCH), 256, 0, stream>>>(
            spatial, partials, nullptr, 0);
        accum_recompute_kernel<<<dim3(FB_BANDS, BATCH), 512, 0, stream>>>(
            point_rates, gia, coords, partials, out);
    }
}

// Round 12
// 174.881 us; speedup vs baseline: 2.8000x; 1.0198x over previous
//
#include <hip/hip_runtime.h>
#include <math.h>

// Problem constants: B=32, N_SOURCES=262144, H=W=256
#define BATCH 32
#define NSRC  262144
#define HH    256
#define WW    256
#define HW    (HH * WW)
#define NBLK  16                 // partial-reduce blocks per batch

// ---------- direct (count-free) path ----------
#define DBANDS 32
#define DBAND_PIX (HW / DBANDS)  // 2048 px (8 rows) -> 8KB acc + 8KB gia LDS
#define DCAP   9216              // slots per (batch,band) bin; E[n]=8192, sd~89
#define SPILL_CAP 131072
//   [0, 8192)        float4 partials[BATCH][NBLK]
//   [8192, 12288)    u32 cursors[BATCH*DBANDS]  (1024)
//   [12288, 12292)   u32 spill_cnt
//   [16384, +1MB)    uint2 spill[SPILL_CAP]
//   [1064960, ...)   u32 arena[BATCH*DBANDS][DCAP]  entry = pix11 | bf16(pr)<<16
#define WS_DCURS_OFF  8192
#define WS_DSPCNT_OFF 12288
#define WS_DSPILL_OFF 16384
#define WS_DARENA_OFF (WS_DSPILL_OFF + SPILL_CAP * 8)
#define WS_DIRECT_BYTES (WS_DARENA_OFF + (size_t)BATCH * DBANDS * DCAP * 4)

// ---------- R11 fallback (exact 3-pass) ----------
#define NBANDS 16
#define BAND_PIX (HW / NBANDS)
#define ARENA_CAP (NSRC + 48)
#define WS_COUNTS_OFF  8192
#define WS_CURSORS_OFF 10240
#define WS_ARENA_OFF   12288
#define WS_BIN_BYTES   (WS_ARENA_OFF + (size_t)BATCH * ARENA_CAP * 4)
#define FB_BANDS 8
#define FB_BAND_PIX (HW / FB_BANDS)

// ---------- Kernel A: per-batch bounding-box partials (+ zero small tables) ----------
__global__ void box_kernel(const float* __restrict__ spatial,
                           float4* __restrict__ partials,
                           unsigned int* __restrict__ zero_tab,  // may be null
                           int zero_n) {
    const int b   = blockIdx.y;
    const int blk = blockIdx.x;
    const int tid = threadIdx.x;  // 0..255

    if (zero_tab && blk == 0 && b == 0) {
        for (int j = tid; j < zero_n; j += 256) zero_tab[j] = 0u;
    }

    const int chunk = HW / NBLK;  // 4096
    const float* xs = spatial + (size_t)b * 2 * HW + (size_t)blk * chunk;
    const float* ys = xs + HW;

    float xmn = 1e30f, xmx = -1e30f, ymn = 1e30f, ymx = -1e30f;
    const float4* xs4 = (const float4*)xs;
    const float4* ys4 = (const float4*)ys;
#pragma unroll
    for (int k = 0; k < 4; k++) {
        float4 vx = xs4[k * 256 + tid];
        float4 vy = ys4[k * 256 + tid];
        xmn = fminf(xmn, fminf(fminf(vx.x, vx.y), fminf(vx.z, vx.w)));
        xmx = fmaxf(xmx, fmaxf(fmaxf(vx.x, vx.y), fmaxf(vx.z, vx.w)));
        ymn = fminf(ymn, fminf(fminf(vy.x, vy.y), fminf(vy.z, vy.w)));
        ymx = fmaxf(ymx, fmaxf(fmaxf(vy.x, vy.y), fmaxf(vy.z, vy.w)));
    }
#pragma unroll
    for (int off = 32; off > 0; off >>= 1) {
        xmn = fminf(xmn, __shfl_down(xmn, off));
        xmx = fmaxf(xmx, __shfl_down(xmx, off));
        ymn = fminf(ymn, __shfl_down(ymn, off));
        ymx = fmaxf(ymx, __shfl_down(ymx, off));
    }
    __shared__ float4 s[4];
    if ((tid & 63) == 0) s[tid >> 6] = make_float4(xmn, xmx, ymn, ymx);
    __syncthreads();
    if (tid == 0) {
        float4 r = s[0];
#pragma unroll
        for (int wv = 1; wv < 4; wv++) {
            float4 t = s[wv];
            r.x = fminf(r.x, t.x); r.y = fmaxf(r.y, t.y);
            r.z = fminf(r.z, t.z); r.w = fmaxf(r.w, t.w);
        }
        partials[b * NBLK + blk] = r;
    }
}

__device__ __forceinline__ float4 fold_box(const float4* __restrict__ partials,
                                           int b, int tid, float4* sbox) {
    if (tid < 64) {
        float4 p = make_float4(1e30f, -1e30f, 1e30f, -1e30f);
        if (tid < NBLK) p = partials[b * NBLK + tid];
        float xmn = p.x, xmx = p.y, ymn = p.z, ymx = p.w;
#pragma unroll
        for (int off = 8; off > 0; off >>= 1) {
            xmn = fminf(xmn, __shfl_down(xmn, off));
            xmx = fmaxf(xmx, __shfl_down(xmx, off));
            ymn = fminf(ymn, __shfl_down(ymn, off));
            ymx = fmaxf(ymx, __shfl_down(ymx, off));
        }
        if (tid == 0) *sbox = make_float4(xmn, xmx, ymn, ymx);
    }
    __syncthreads();
    return *sbox;
}

// Verified reference pipeline (R8): reciprocal-multiply, correctly-rounded f32,
// half-even rounding, clip to [0,255].
__device__ __forceinline__ int route_of(float cx, float cy, float xmin,
                                        float ymin, float invx, float invy) {
    const float nx = __fmul_rn(__fsub_rn(cx, xmin), invx);
    const float ny = __fmul_rn(__fsub_rn(cy, ymin), invy);
    int px = (int)rintf(__fmul_rn(nx, 255.0f));
    int py = (int)rintf(__fmul_rn(ny, 255.0f));
    px = px < 0 ? 0 : (px > 255 ? 255 : px);
    py = py < 0 ? 0 : (py > 255 ? 255 : py);
    return py * WW + px;
}

// ================= DIRECT PATH (count-free, fixed-cap bins + spill) =================

__global__ __launch_bounds__(256) void scatter_direct_kernel(
    const float* __restrict__ point_rates, const float2* __restrict__ coords,
    const float4* __restrict__ partials, unsigned int* __restrict__ cursors,
    unsigned int* __restrict__ arena, unsigned int* __restrict__ spill_cnt,
    uint2* __restrict__ spill) {
    const int b   = blockIdx.y;
    const int tid = threadIdx.x;
    __shared__ float4 sbox;
    __shared__ unsigned int hist[DBANDS];
    __shared__ unsigned int bbase[DBANDS];
    const float4 box = fold_box(partials, b, tid, &sbox);
    const float xmin = box.x, xmax = box.y, ymin = box.z, ymax = box.w;
    const float invx = __fdiv_rn(1.0f, __fsub_rn(xmax, xmin));
    const float invy = __fdiv_rn(1.0f, __fsub_rn(ymax, ymin));
    if (tid < DBANDS) hist[tid] = 0u;
    __syncthreads();

    const float* prb = point_rates + (size_t)b * NSRC;
    const int base = blockIdx.x * 4096;

    unsigned int ent[16];
    unsigned short rnk[16];
    unsigned char  bin[16];
#pragma unroll
    for (int k = 0; k < 16; k++) {
        const int i = base + k * 256 + tid;
        const float2 c = coords[i];
        bin[k] = 0xFF;
        if (c.x < xmin || c.x > xmax || c.y < ymin || c.y > ymax) continue;
        const int idx = route_of(c.x, c.y, xmin, ymin, invx, invy);
        // f32 -> bf16 RNE of point_rate; gia multiply deferred to accumulate.
        const unsigned int bits = __float_as_uint(prb[i]);
        const unsigned int b16 = (bits + 0x7FFFu + ((bits >> 16) & 1u)) >> 16;
        const int z = idx >> 11;  // band of 2048 px
        rnk[k] = (unsigned short)atomicAdd(&hist[z], 1u);
        ent[k] = (unsigned int)(idx & (DBAND_PIX - 1)) | (b16 << 16);
        bin[k] = (unsigned char)z;
    }
    __syncthreads();
    if (tid < DBANDS)
        bbase[tid] = atomicAdd(&cursors[b * DBANDS + tid], hist[tid]);
    __syncthreads();
#pragma unroll
    for (int k = 0; k < 16; k++) {
        if (bin[k] == 0xFF) continue;
        const unsigned int slot = bbase[bin[k]] + rnk[k];
        if (slot < DCAP) {
            arena[((size_t)b * DBANDS + bin[k]) * DCAP + slot] = ent[k];
        } else {
            // bin overflow (pathological distribution): spill globally
            const unsigned int pos = atomicAdd(spill_cnt, 1u);
            if (pos < SPILL_CAP) {
                const unsigned int pix =
                    ((unsigned int)bin[k] << 11) | (ent[k] & (DBAND_PIX - 1));
                spill[pos] = make_uint2(((unsigned int)b << 16) | pix,
                                        ent[k] & 0xFFFF0000u);
            }
        }
    }
}

__global__ __launch_bounds__(512) void accum_direct_kernel(
    const unsigned int* __restrict__ arena, const float* __restrict__ gia,
    const unsigned int* __restrict__ cursors, float* __restrict__ out) {
    __shared__ float acc[DBAND_PIX];
    __shared__ float gld[DBAND_PIX];
    const int z   = blockIdx.x;
    const int b   = blockIdx.y;
    const int tid = threadIdx.x;  // 0..511

    ((float4*)gld)[tid] =
        ((const float4*)(gia + (size_t)b * HW + (size_t)z * DBAND_PIX))[tid];
    ((float4*)acc)[tid] = make_float4(0.f, 0.f, 0.f, 0.f);
    __syncthreads();

    unsigned int n = cursors[b * DBANDS + z];
    if (n > DCAP) n = DCAP;
    const uint4* a4 = (const uint4*)(arena + ((size_t)b * DBANDS + z) * DCAP);

#define DO_E(w)                                                              \
    {                                                                        \
        const unsigned int _p = (w) & (DBAND_PIX - 1);                       \
        atomicAdd(&acc[_p], __fmul_rn(__uint_as_float((w) & 0xFFFF0000u),    \
                                      gld[_p]));                             \
    }
    const unsigned int n4 = n >> 2;
    unsigned int j = tid;
    for (; j + 512 < n4; j += 1024) {          // 2 uint4 in flight
        const uint4 e1 = a4[j];
        const uint4 e2 = a4[j + 512];
        DO_E(e1.x) DO_E(e1.y) DO_E(e1.z) DO_E(e1.w)
        DO_E(e2.x) DO_E(e2.y) DO_E(e2.z) DO_E(e2.w)
    }
    for (; j < n4; j += 512) {
        const uint4 e = a4[j];
        DO_E(e.x) DO_E(e.y) DO_E(e.z) DO_E(e.w)
    }
    const unsigned int* a1 = (const unsigned int*)a4;
    for (unsigned int jj = (n4 << 2) + tid; jj < n; jj += 512) {
        const unsigned int w = a1[jj];
        DO_E(w)
    }
#undef DO_E
    __syncthreads();

    ((float4*)(out + (size_t)b * HW + (size_t)z * DBAND_PIX))[tid] =
        ((const float4*)acc)[tid];
}

__global__ void spill_kernel(const unsigned int* __restrict__ spill_cnt,
                             const uint2* __restrict__ spill,
                             const float* __restrict__ gia,
                             float* __restrict__ out) {
    unsigned int n = *spill_cnt;
    if (n > SPILL_CAP) n = SPILL_CAP;
    for (unsigned int j = blockIdx.x * 256 + threadIdx.x; j < n;
         j += gridDim.x * 256) {
        const uint2 e = spill[j];
        const unsigned int b = e.x >> 16;
        const unsigned int pix = e.x & 0xFFFFu;
        const float v = __uint_as_float(e.y);
        atomicAdd(&out[(size_t)b * HW + pix],
                  __fmul_rn(v, gia[(size_t)b * HW + pix]));
    }
}

// ================= R11 FALLBACK PATH (exact 3-pass) =================

__device__ __forceinline__ void compute_starts(const unsigned int* __restrict__ counts,
                                               int b, int tid,
                                               unsigned int* sstarts) {
    if (tid == 0) {
        unsigned int s = 0;
        for (int z = 0; z < NBANDS; z++) {
            s = (s + 3u) & ~3u;
            sstarts[z] = s;
            s += counts[b * NBANDS + z];
        }
    }
    __syncthreads();
}

__global__ __launch_bounds__(256) void count_kernel(
    const float2* __restrict__ coords, const float4* __restrict__ partials,
    unsigned int* __restrict__ counts) {
    const int b   = blockIdx.y;
    const int tid = threadIdx.x;
    __shared__ float4 sbox;
    __shared__ unsigned int hist[NBANDS];
    const float4 box = fold_box(partials, b, tid, &sbox);
    const float xmin = box.x, xmax = box.y, ymin = box.z, ymax = box.w;
    const float invx = __fdiv_rn(1.0f, __fsub_rn(xmax, xmin));
    const float invy = __fdiv_rn(1.0f, __fsub_rn(ymax, ymin));
    if (tid < NBANDS) hist[tid] = 0u;
    __syncthreads();

    const int base = blockIdx.x * 4096;
#pragma unroll 4
    for (int k = 0; k < 16; k++) {
        const int i = base + k * 256 + tid;
        const float2 c = coords[i];
        if (c.x < xmin || c.x > xmax || c.y < ymin || c.y > ymax) continue;
        const int idx = route_of(c.x, c.y, xmin, ymin, invx, invy);
        atomicAdd(&hist[idx / BAND_PIX], 1u);
    }
    __syncthreads();
    if (tid < NBANDS) atomicAdd(&counts[b * NBANDS + tid], hist[tid]);
}

__global__ __launch_bounds__(256) void scatter_bin_kernel(
    const float* __restrict__ point_rates, const float2* __restrict__ coords,
    const float4* __restrict__ partials, const unsigned int* __restrict__ counts,
    unsigned int* __restrict__ cursors, unsigned int* __restrict__ arena) {
    const int b   = blockIdx.y;
    const int tid = threadIdx.x;
    __shared__ float4 sbox;
    __shared__ unsigned int sstarts[NBANDS];
    __shared__ unsigned int hist[NBANDS];
    __shared__ unsigned int bbase[NBANDS];
    const float4 box = fold_box(partials, b, tid, &sbox);
    compute_starts(counts, b, tid, sstarts);
    const float xmin = box.x, xmax = box.y, ymin = box.z, ymax = box.w;
    const float invx = __fdiv_rn(1.0f, __fsub_rn(xmax, xmin));
    const float invy = __fdiv_rn(1.0f, __fsub_rn(ymax, ymin));
    if (tid < NBANDS) hist[tid] = 0u;
    __syncthreads();

    const float* prb = point_rates + (size_t)b * NSRC;
    const int base = blockIdx.x * 4096;

    unsigned int ent[16];
    unsigned short rnk[16];
    unsigned char  bin[16];
#pragma unroll
    for (int k = 0; k < 16; k++) {
        const int i = base + k * 256 + tid;
        const float2 c = coords[i];
        bin[k] = 0xFF;
        if (c.x < xmin || c.x > xmax || c.y < ymin || c.y > ymax) continue;
        const int idx = route_of(c.x, c.y, xmin, ymin, invx, invy);
        const unsigned int bits = __float_as_uint(prb[i]);
        const unsigned int b16 = (bits + 0x7FFFu + ((bits >> 16) & 1u)) >> 16;
        const int z = idx / BAND_PIX;
        rnk[k] = (unsigned short)atomicAdd(&hist[z], 1u);
        ent[k] = (unsigned int)(idx & (BAND_PIX - 1)) | (b16 << 16);
        bin[k] = (unsigned char)z;
    }
    __syncthreads();
    if (tid < NBANDS)
        bbase[tid] = sstarts[tid] + atomicAdd(&cursors[b * NBANDS + tid], hist[tid]);
    __syncthreads();
    unsigned int* ab = arena + (size_t)b * ARENA_CAP;
#pragma unroll
    for (int k = 0; k < 16; k++) {
        if (bin[k] != 0xFF) ab[bbase[bin[k]] + rnk[k]] = ent[k];
    }
}

__global__ __launch_bounds__(512) void accum_bin_kernel(
    const unsigned int* __restrict__ arena, const float* __restrict__ gia,
    const unsigned int* __restrict__ counts, float* __restrict__ out) {
    __shared__ float acc[BAND_PIX];
    __shared__ float gld[BAND_PIX];
    __shared__ unsigned int sstarts[NBANDS];
    const int z   = blockIdx.x;
    const int b   = blockIdx.y;
    const int tid = threadIdx.x;

    compute_starts(counts, b, tid, sstarts);

    const float4* g4 = (const float4*)(gia + (size_t)b * HW + (size_t)z * BAND_PIX);
    float4* gl4 = (float4*)gld;
#pragma unroll
    for (int j = 0; j < BAND_PIX / 4 / 512; j++) gl4[j * 512 + tid] = g4[j * 512 + tid];
#pragma unroll
    for (int j = 0; j < BAND_PIX / 512; j++) acc[j * 512 + tid] = 0.f;
    __syncthreads();

    const unsigned int start = sstarts[z];
    const unsigned int n     = counts[b * NBANDS + z];
    const uint4* a4 = (const uint4*)(arena + (size_t)b * ARENA_CAP + start);

    const unsigned int n4 = n >> 2;
#define DO_E(w)                                                              \
    atomicAdd(&acc[(w) & (BAND_PIX - 1)],                                    \
              __fmul_rn(__uint_as_float((w) & 0xFFFF0000u),                  \
                        gld[(w) & (BAND_PIX - 1)]));
    for (unsigned int j = tid; j < n4; j += 512) {
        const uint4 e = a4[j];
        DO_E(e.x) DO_E(e.y) DO_E(e.z) DO_E(e.w)
    }
    const unsigned int* a1 = (const unsigned int*)a4;
    for (unsigned int j = (n4 << 2) + tid; j < n; j += 512) {
        const unsigned int w = a1[j];
        DO_E(w)
    }
#undef DO_E
    __syncthreads();

    float4* o4 = (float4*)(out + (size_t)b * HW + (size_t)z * BAND_PIX);
    const float4* c4 = (const float4*)acc;
#pragma unroll
    for (int j = 0; j < BAND_PIX / 4 / 512; j++) o4[j * 512 + tid] = c4[j * 512 + tid];
}

__global__ __launch_bounds__(512) void accum_recompute_kernel(
    const float* __restrict__ point_rates, const float* __restrict__ gia,
    const float2* __restrict__ coords, const float4* __restrict__ partials,
    float* __restrict__ out) {
    __shared__ float acc[FB_BAND_PIX];
    __shared__ float4 sbox;
    const int z   = blockIdx.x;
    const int b   = blockIdx.y;
    const int tid = threadIdx.x;

    const float4 box = fold_box(partials, b, tid, &sbox);
    const float xmin = box.x, xmax = box.y, ymin = box.z, ymax = box.w;
    const float invx = __fdiv_rn(1.0f, __fsub_rn(xmax, xmin));
    const float invy = __fdiv_rn(1.0f, __fsub_rn(ymax, ymin));

    for (int j = tid; j < FB_BAND_PIX; j += 512) acc[j] = 0.f;
    __syncthreads();

    const float* prb = point_rates + (size_t)b * NSRC;
    const float* gb  = gia + (size_t)b * HW;
    const int lo = z * FB_BAND_PIX, hi = lo + FB_BAND_PIX;

    for (int i = tid; i < NSRC; i += 512) {
        const float2 c = coords[i];
        if (c.x < xmin || c.x > xmax || c.y < ymin || c.y > ymax) continue;
        const int idx = route_of(c.x, c.y, xmin, ymin, invx, invy);
        if (idx < lo || idx >= hi) continue;
        const float em = __fmul_rn(prb[i], gb[idx]);
        atomicAdd(&acc[idx - lo], em);
    }
    __syncthreads();

    float4* o4 = (float4*)(out + (size_t)b * HW + (size_t)z * FB_BAND_PIX);
    const float4* a4 = (const float4*)acc;
    for (int j = tid; j < FB_BAND_PIX / 4; j += 512) o4[j] = a4[j];
}

extern "C" void kernel_launch(void* const* d_in, const int* in_sizes, int n_in,
                              void* d_out, int out_size, void* d_ws, size_t ws_size,
                              hipStream_t stream) {
    const float* point_rates = (const float*)d_in[0];   // (B, NSRC)
    const float* spatial     = (const float*)d_in[1];   // (B, 2, H, W)
    const float* gia         = (const float*)d_in[2];   // (B, H, W)
    const float2* coords     = (const float2*)d_in[3];  // (NSRC, 2)
    float* out = (float*)d_out;                         // (B, 1, H, W)

    char* ws = (char*)d_ws;
    float4* partials = (float4*)ws;

    if (ws_size >= WS_DIRECT_BYTES) {
        unsigned int* cursors   = (unsigned int*)(ws + WS_DCURS_OFF);
        unsigned int* spill_cnt = (unsigned int*)(ws + WS_DSPCNT_OFF);
        uint2*        spill     = (uint2*)(ws + WS_DSPILL_OFF);
        unsigned int* arena     = (unsigned int*)(ws + WS_DARENA_OFF);

        // cursors (1024 u32) + spill_cnt are contiguous: zero 1025 u32
        box_kernel<<<dim3(NBLK, BATCH), 256, 0, stream>>>(
            spatial, partials, cursors, BATCH * DBANDS + 1);
        scatter_direct_kernel<<<dim3(NSRC / 4096, BATCH), 256, 0, stream>>>(
            point_rates, coords, partials, cursors, arena, spill_cnt, spill);
        accum_direct_kernel<<<dim3(DBANDS, BATCH), 512, 0, stream>>>(
            arena, gia, cursors, out);
        spill_kernel<<<4, 256, 0, stream>>>(spill_cnt, spill, gia, out);
    } else if (ws_size >= WS_BIN_BYTES) {
        unsigned int* counts  = (unsigned int*)(ws + WS_COUNTS_OFF);
        unsigned int* cursors = (unsigned int*)(ws + WS_CURSORS_OFF);
        unsigned int* arena   = (unsigned int*)(ws + WS_ARENA_OFF);

        box_kernel<<<dim3(NBLK, BATCH), 256, 0, stream>>>(
            spatial, partials, counts, 2 * BATCH * NBANDS + 512 / 4);
        count_kernel<<<dim3(NSRC / 4096, BATCH), 256, 0, stream>>>(
            coords, partials, counts);
        scatter_bin_kernel<<<dim3(NSRC / 4096, BATCH), 256, 0, stream>>>(
            point_rates, coords, partials, counts, cursors, arena);
        accum_bin_kernel<<<dim3(NBANDS, BATCH), 512, 0, stream>>>(
            arena, gia, counts, out);
    } else {
        box_kernel<<<dim3(NBLK, BATCH), 256, 0, stream>>>(
            spatial, partials, nullptr, 0);
        accum_recompute_kernel<<<dim3(FB_BANDS, BATCH), 512, 0, stream>>>(
            point_rates, gia, coords, partials, out);
    }
}

// Round 13
// 172.175 us; speedup vs baseline: 2.8440x; 1.0157x over previous
//
#include <hip/hip_runtime.h>
#include <math.h>

// Problem constants: B=32, N_SOURCES=262144, H=W=256
#define BATCH 32
#define NSRC  262144
#define HH    256
#define WW    256
#define HW    (HH * WW)
#define NBLK  16                 // partial-reduce blocks per batch

// ---------- ballot-binned path ----------
#define ZBANDS 8
#define ZBAND_PIX (HW / ZBANDS)    // 8192 px (32 rows) -> 32 KB acc LDS
#define ZCAP   36864               // slots per (batch,band); E=32768, sd~169
#define SPILL_CAP 131072
//   [0, 8192)        float4 partials[BATCH][NBLK]
//   [8192, 9216)     u32 cursors[BATCH*ZBANDS] (256)
//   [9216, 9220)     u32 spill_cnt
//   [16384, +1MB)    uint2 spill[SPILL_CAP]
//   [1064960, ...)   u32 arena[BATCH*ZBANDS][ZCAP]  entry = pix13 | bf16(pr)<<16
#define WS_ZCURS_OFF  8192
#define WS_ZSPCNT_OFF 9216
#define WS_ZSPILL_OFF 16384
#define WS_ZARENA_OFF (WS_ZSPILL_OFF + SPILL_CAP * 8)
#define WS_Z_BYTES    (WS_ZARENA_OFF + (size_t)BATCH * ZBANDS * ZCAP * 4)

#define FB_BANDS 8
#define FB_BAND_PIX (HW / FB_BANDS)

// ---------- Kernel A: per-batch bounding-box partials (+ zero small tables) ----------
__global__ void box_kernel(const float* __restrict__ spatial,
                           float4* __restrict__ partials,
                           unsigned int* __restrict__ zero_tab,  // may be null
                           int zero_n) {
    const int b   = blockIdx.y;
    const int blk = blockIdx.x;
    const int tid = threadIdx.x;  // 0..255

    if (zero_tab && blk == 0 && b == 0) {
        for (int j = tid; j < zero_n; j += 256) zero_tab[j] = 0u;
    }

    const int chunk = HW / NBLK;  // 4096
    const float* xs = spatial + (size_t)b * 2 * HW + (size_t)blk * chunk;
    const float* ys = xs + HW;

    float xmn = 1e30f, xmx = -1e30f, ymn = 1e30f, ymx = -1e30f;
    const float4* xs4 = (const float4*)xs;
    const float4* ys4 = (const float4*)ys;
#pragma unroll
    for (int k = 0; k < 4; k++) {
        float4 vx = xs4[k * 256 + tid];
        float4 vy = ys4[k * 256 + tid];
        xmn = fminf(xmn, fminf(fminf(vx.x, vx.y), fminf(vx.z, vx.w)));
        xmx = fmaxf(xmx, fmaxf(fmaxf(vx.x, vx.y), fmaxf(vx.z, vx.w)));
        ymn = fminf(ymn, fminf(fminf(vy.x, vy.y), fminf(vy.z, vy.w)));
        ymx = fmaxf(ymx, fmaxf(fmaxf(vy.x, vy.y), fmaxf(vy.z, vy.w)));
    }
#pragma unroll
    for (int off = 32; off > 0; off >>= 1) {
        xmn = fminf(xmn, __shfl_down(xmn, off));
        xmx = fmaxf(xmx, __shfl_down(xmx, off));
        ymn = fminf(ymn, __shfl_down(ymn, off));
        ymx = fmaxf(ymx, __shfl_down(ymx, off));
    }
    __shared__ float4 s[4];
    if ((tid & 63) == 0) s[tid >> 6] = make_float4(xmn, xmx, ymn, ymx);
    __syncthreads();
    if (tid == 0) {
        float4 r = s[0];
#pragma unroll
        for (int wv = 1; wv < 4; wv++) {
            float4 t = s[wv];
            r.x = fminf(r.x, t.x); r.y = fmaxf(r.y, t.y);
            r.z = fminf(r.z, t.z); r.w = fmaxf(r.w, t.w);
        }
        partials[b * NBLK + blk] = r;
    }
}

__device__ __forceinline__ float4 fold_box(const float4* __restrict__ partials,
                                           int b, int tid, float4* sbox) {
    if (tid < 64) {
        float4 p = make_float4(1e30f, -1e30f, 1e30f, -1e30f);
        if (tid < NBLK) p = partials[b * NBLK + tid];
        float xmn = p.x, xmx = p.y, ymn = p.z, ymx = p.w;
#pragma unroll
        for (int off = 8; off > 0; off >>= 1) {
            xmn = fminf(xmn, __shfl_down(xmn, off));
            xmx = fmaxf(xmx, __shfl_down(xmx, off));
            ymn = fminf(ymn, __shfl_down(ymn, off));
            ymx = fmaxf(ymx, __shfl_down(ymx, off));
        }
        if (tid == 0) *sbox = make_float4(xmn, xmx, ymn, ymx);
    }
    __syncthreads();
    return *sbox;
}

// Verified reference pipeline (R8): reciprocal-multiply, correctly-rounded f32,
// half-even rounding, clip to [0,255].
__device__ __forceinline__ int route_of(float cx, float cy, float xmin,
                                        float ymin, float invx, float invy) {
    const float nx = __fmul_rn(__fsub_rn(cx, xmin), invx);
    const float ny = __fmul_rn(__fsub_rn(cy, ymin), invy);
    int px = (int)rintf(__fmul_rn(nx, 255.0f));
    int py = (int)rintf(__fmul_rn(ny, 255.0f));
    px = px < 0 ? 0 : (px > 255 ? 255 : px);
    py = py < 0 ? 0 : (py > 255 ? 255 : py);
    return py * WW + px;
}

// ================= BALLOT-BINNED PATH =================
// Scatter: ranks via wave ballots (zero LDS atomics); entry = pix13|bf16(pr).
// Accum:   LDS atomicAdd of pr only (g factored out: out = g * sum(pr)).

__global__ __launch_bounds__(256) void scatter_ballot_kernel(
    const float* __restrict__ point_rates, const float2* __restrict__ coords,
    const float4* __restrict__ partials, unsigned int* __restrict__ cursors,
    unsigned int* __restrict__ arena, unsigned int* __restrict__ spill_cnt,
    uint2* __restrict__ spill) {
    const int b    = blockIdx.y;
    const int tid  = threadIdx.x;
    const int wave = tid >> 6;
    const int lane = tid & 63;
    __shared__ float4 sbox;
    __shared__ unsigned int wtot[4][ZBANDS];
    __shared__ unsigned int wbase[4][ZBANDS];

    const float4 box = fold_box(partials, b, tid, &sbox);
    const float xmin = box.x, xmax = box.y, ymin = box.z, ymax = box.w;
    const float invx = __fdiv_rn(1.0f, __fsub_rn(xmax, xmin));
    const float invy = __fdiv_rn(1.0f, __fsub_rn(ymax, ymin));

    const unsigned long long below =
        (lane == 63) ? 0x7FFFFFFFFFFFFFFFull : ((1ull << lane) - 1ull);

    const float* prb = point_rates + (size_t)b * NSRC;
    const int base = blockIdx.x * 4096;

    unsigned int cur[ZBANDS];
#pragma unroll
    for (int z = 0; z < ZBANDS; z++) cur[z] = 0u;

    unsigned int ent[16];
    unsigned int meta[16];  // (z<<16)|rank_in_wave, or 0xFFFFFFFF if skipped

#pragma unroll
    for (int k = 0; k < 16; k++) {
        const int i = base + k * 256 + tid;
        const float2 c = coords[i];
        const float  pr = prb[i];
        const bool valid =
            !(c.x < xmin || c.x > xmax || c.y < ymin || c.y > ymax);
        const int idx = route_of(c.x, c.y, xmin, ymin, invx, invy);
        const int z = valid ? (idx >> 13) : ZBANDS;  // band of 8192 px
        // f32 -> bf16 RNE of point_rate (>=0, finite)
        const unsigned int bits = __float_as_uint(pr);
        const unsigned int b16 = (bits + 0x7FFFu + ((bits >> 16) & 1u)) >> 16;
        ent[k] = (unsigned int)(idx & (ZBAND_PIX - 1)) | (b16 << 16);

        // Ballot ranks: wave-uniform per-bin cursors live in (scalar) regs.
        unsigned long long mown = 0ull;
        unsigned int curbase = 0u;
#pragma unroll
        for (int zz = 0; zz < ZBANDS; zz++) {
            const bool pz = (z == zz);
            const unsigned long long m = __ballot(pz);
            if (pz) { mown = m; curbase = cur[zz]; }
            cur[zz] += (unsigned int)__popcll(m);
        }
        meta[k] = valid
            ? (((unsigned int)z << 16) |
               (curbase + (unsigned int)__popcll(mown & below)))
            : 0xFFFFFFFFu;
    }

    // publish per-wave totals (non-atomic: each wave owns its row)
    if (lane == 0) {
#pragma unroll
        for (int z = 0; z < ZBANDS; z++) wtot[wave][z] = cur[z];
    }
    __syncthreads();

    // wave 0, lane z<8: fold 4 waves, reserve global range, compute wave bases
    if (wave == 0 && lane < ZBANDS) {
        unsigned int t0 = wtot[0][lane], t1 = wtot[1][lane],
                     t2 = wtot[2][lane], t3 = wtot[3][lane];
        unsigned int tot = t0 + t1 + t2 + t3;
        unsigned int g = atomicAdd(&cursors[b * ZBANDS + lane], tot);
        wbase[0][lane] = g;
        wbase[1][lane] = g + t0;
        wbase[2][lane] = g + t0 + t1;
        wbase[3][lane] = g + t0 + t1 + t2;
    }
    __syncthreads();

#pragma unroll
    for (int k = 0; k < 16; k++) {
        const unsigned int mt = meta[k];
        if (mt == 0xFFFFFFFFu) continue;
        const unsigned int z = mt >> 16;
        const unsigned int slot = wbase[wave][z] + (mt & 0xFFFFu);
        if (slot < ZCAP) {
            arena[((size_t)b * ZBANDS + z) * ZCAP + slot] = ent[k];
        } else {
            // bin overflow (pathological distribution): spill globally
            const unsigned int pos = atomicAdd(spill_cnt, 1u);
            if (pos < SPILL_CAP) {
                const unsigned int pix =
                    (z << 13) | (ent[k] & (ZBAND_PIX - 1));
                const int i = base + k * 256 + tid;
                spill[pos] = make_uint2(((unsigned int)b << 16) | pix,
                                        __float_as_uint(prb[i]));
            }
        }
    }
}

__global__ __launch_bounds__(1024) void accum_g_kernel(
    const unsigned int* __restrict__ arena, const float* __restrict__ gia,
    const unsigned int* __restrict__ cursors, float* __restrict__ out) {
    __shared__ float acc[ZBAND_PIX];  // 32 KB
    const int z   = blockIdx.x;
    const int b   = blockIdx.y;
    const int tid = threadIdx.x;  // 0..1023

#pragma unroll
    for (int j = 0; j < ZBAND_PIX / 4 / 1024; j++)
        ((float4*)acc)[j * 1024 + tid] = make_float4(0.f, 0.f, 0.f, 0.f);
    __syncthreads();

    unsigned int n = cursors[b * ZBANDS + z];
    if (n > ZCAP) n = ZCAP;
    const uint4* a4 = (const uint4*)(arena + ((size_t)b * ZBANDS + z) * ZCAP);

    // entry = pix13 | bf16(pr)<<16 ; accumulate pr only (g factored out)
#define DO_E(w)                                                              \
    atomicAdd(&acc[(w) & (ZBAND_PIX - 1)],                                   \
              __uint_as_float((w) & 0xFFFF0000u));
    const unsigned int n4 = n >> 2;
    unsigned int j = tid;
    for (; j + 1024 < n4; j += 2048) {  // 2 uint4 in flight
        const uint4 e1 = a4[j];
        const uint4 e2 = a4[j + 1024];
        DO_E(e1.x) DO_E(e1.y) DO_E(e1.z) DO_E(e1.w)
        DO_E(e2.x) DO_E(e2.y) DO_E(e2.z) DO_E(e2.w)
    }
    for (; j < n4; j += 1024) {
        const uint4 e = a4[j];
        DO_E(e.x) DO_E(e.y) DO_E(e.z) DO_E(e.w)
    }
    const unsigned int* a1 = (const unsigned int*)a4;
    for (unsigned int jj = (n4 << 2) + tid; jj < n; jj += 1024) {
        const unsigned int w = a1[jj];
        DO_E(w)
    }
#undef DO_E
    __syncthreads();

    // out = acc * g, coalesced
    const float4* g4 = (const float4*)(gia + (size_t)b * HW + (size_t)z * ZBAND_PIX);
    float4* o4 = (float4*)(out + (size_t)b * HW + (size_t)z * ZBAND_PIX);
#pragma unroll
    for (int jj = 0; jj < ZBAND_PIX / 4 / 1024; jj++) {
        const float4 a = ((const float4*)acc)[jj * 1024 + tid];
        const float4 g = g4[jj * 1024 + tid];
        o4[jj * 1024 + tid] = make_float4(__fmul_rn(a.x, g.x),
                                          __fmul_rn(a.y, g.y),
                                          __fmul_rn(a.z, g.z),
                                          __fmul_rn(a.w, g.w));
    }
}

__global__ void spill_kernel(const unsigned int* __restrict__ spill_cnt,
                             const uint2* __restrict__ spill,
                             const float* __restrict__ gia,
                             float* __restrict__ out) {
    unsigned int n = *spill_cnt;
    if (n > SPILL_CAP) n = SPILL_CAP;
    for (unsigned int j = blockIdx.x * 256 + threadIdx.x; j < n;
         j += gridDim.x * 256) {
        const uint2 e = spill[j];
        const unsigned int b = e.x >> 16;
        const unsigned int pix = e.x & 0xFFFFu;
        const float pr = __uint_as_float(e.y);
        atomicAdd(&out[(size_t)b * HW + pix],
                  __fmul_rn(pr, gia[(size_t)b * HW + pix]));
    }
}

// ================= FALLBACK (exact, small-ws) =================

__global__ __launch_bounds__(512) void accum_recompute_kernel(
    const float* __restrict__ point_rates, const float* __restrict__ gia,
    const float2* __restrict__ coords, const float4* __restrict__ partials,
    float* __restrict__ out) {
    __shared__ float acc[FB_BAND_PIX];
    __shared__ float4 sbox;
    const int z   = blockIdx.x;
    const int b   = blockIdx.y;
    const int tid = threadIdx.x;

    const float4 box = fold_box(partials, b, tid, &sbox);
    const float xmin = box.x, xmax = box.y, ymin = box.z, ymax = box.w;
    const float invx = __fdiv_rn(1.0f, __fsub_rn(xmax, xmin));
    const float invy = __fdiv_rn(1.0f, __fsub_rn(ymax, ymin));

    for (int j = tid; j < FB_BAND_PIX; j += 512) acc[j] = 0.f;
    __syncthreads();

    const float* prb = point_rates + (size_t)b * NSRC;
    const float* gb  = gia + (size_t)b * HW;
    const int lo = z * FB_BAND_PIX, hi = lo + FB_BAND_PIX;

    for (int i = tid; i < NSRC; i += 512) {
        const float2 c = coords[i];
        if (c.x < xmin || c.x > xmax || c.y < ymin || c.y > ymax) continue;
        const int idx = route_of(c.x, c.y, xmin, ymin, invx, invy);
        if (idx < lo || idx >= hi) continue;
        const float em = __fmul_rn(prb[i], gb[idx]);
        atomicAdd(&acc[idx - lo], em);
    }
    __syncthreads();

    float4* o4 = (float4*)(out + (size_t)b * HW + (size_t)z * FB_BAND_PIX);
    const float4* a4 = (const float4*)acc;
    for (int j = tid; j < FB_BAND_PIX / 4; j += 512) o4[j] = a4[j];
}

extern "C" void kernel_launch(void* const* d_in, const int* in_sizes, int n_in,
                              void* d_out, int out_size, void* d_ws, size_t ws_size,
                              hipStream_t stream) {
    const float* point_rates = (const float*)d_in[0];   // (B, NSRC)
    const float* spatial     = (const float*)d_in[1];   // (B, 2, H, W)
    const float* gia         = (const float*)d_in[2];   // (B, H, W)
    const float2* coords     = (const float2*)d_in[3];  // (NSRC, 2)
    float* out = (float*)d_out;                         // (B, 1, H, W)

    char* ws = (char*)d_ws;
    float4* partials = (float4*)ws;

    if (ws_size >= WS_Z_BYTES) {
        unsigned int* cursors   = (unsigned int*)(ws + WS_ZCURS_OFF);
        unsigned int* spill_cnt = (unsigned int*)(ws + WS_ZSPCNT_OFF);
        uint2*        spill     = (uint2*)(ws + WS_ZSPILL_OFF);
        unsigned int* arena     = (unsigned int*)(ws + WS_ZARENA_OFF);

        // cursors (256 u32) + spill_cnt contiguous: zero 257 u32
        box_kernel<<<dim3(NBLK, BATCH), 256, 0, stream>>>(
            spatial, partials, cursors, BATCH * ZBANDS + 1);
        scatter_ballot_kernel<<<dim3(NSRC / 4096, BATCH), 256, 0, stream>>>(
            point_rates, coords, partials, cursors, arena, spill_cnt, spill);
        accum_g_kernel<<<dim3(ZBANDS, BATCH), 1024, 0, stream>>>(
            arena, gia, cursors, out);
        spill_kernel<<<4, 256, 0, stream>>>(spill_cnt, spill, gia, out);
    } else {
        box_kernel<<<dim3(NBLK, BATCH), 256, 0, stream>>>(
            spatial, partials, nullptr, 0);
        accum_recompute_kernel<<<dim3(FB_BANDS, BATCH), 512, 0, stream>>>(
            point_rates, gia, coords, partials, out);
    }
}